// Round 1
// baseline (1044.788 us; speedup 1.0000x reference)
//
#include <hip/hip_runtime.h>
#include <math.h>

#define NN   100000
#define NE   1600000
#define DIN  128
#define HID  256
#define NG   64
#define NCLS 10

// ---------------- graph preprocessing ----------------

__global__ void k_deg(const int* __restrict__ dst, int* __restrict__ deg, int n) {
    int e = blockIdx.x * blockDim.x + threadIdx.x;
    if (e < n) atomicAdd(&deg[dst[e]], 1);
}

__global__ void k_dinv(const int* __restrict__ deg, float* __restrict__ dinv, int n) {
    int i = blockIdx.x * blockDim.x + threadIdx.x;
    if (i < n) dinv[i] = rsqrtf((float)(deg[i] + 1));
}

// block sums over chunks of 1024
__global__ void k_bsum(const int* __restrict__ deg, int* __restrict__ bsum, int n) {
    __shared__ int sd[256];
    int t = threadIdx.x;
    int base = blockIdx.x * 1024 + t * 4;
    int s = 0;
#pragma unroll
    for (int i = 0; i < 4; ++i)
        if (base + i < n) s += deg[base + i];
    sd[t] = s; __syncthreads();
    for (int off = 128; off > 0; off >>= 1) {
        if (t < off) sd[t] += sd[t + off];
        __syncthreads();
    }
    if (t == 0) bsum[blockIdx.x] = sd[0];
}

// exclusive scan of <=128 block sums, single block
__global__ void k_scanb(const int* __restrict__ bsum, int* __restrict__ boff, int nb) {
    __shared__ int tmp[128];
    int t = threadIdx.x;
    int v = (t < nb) ? bsum[t] : 0;
    tmp[t] = v; __syncthreads();
    for (int off = 1; off < 128; off <<= 1) {
        int u = (t >= off) ? tmp[t - off] : 0;
        __syncthreads();
        tmp[t] += u;
        __syncthreads();
    }
    if (t < nb) boff[t] = tmp[t] - v;
}

// write exclusive offsets per element
__global__ void k_offs(const int* __restrict__ deg, const int* __restrict__ boff,
                       int* __restrict__ offs, int n) {
    __shared__ int ts[256];
    int t = threadIdx.x;
    int base = blockIdx.x * 1024 + t * 4;
    int v[4]; int s = 0;
#pragma unroll
    for (int i = 0; i < 4; ++i) { v[i] = (base + i < n) ? deg[base + i] : 0; s += v[i]; }
    ts[t] = s; __syncthreads();
    int mine = s;
    for (int off = 1; off < 256; off <<= 1) {
        int u = (t >= off) ? ts[t - off] : 0;
        __syncthreads();
        ts[t] += u;
        __syncthreads();
    }
    int run = ts[t] - mine + boff[blockIdx.x];
#pragma unroll
    for (int i = 0; i < 4; ++i) {
        if (base + i < n) { offs[base + i] = run; run += v[i]; }
    }
}

__global__ void k_fill(const int* __restrict__ src, const int* __restrict__ dst,
                       int* __restrict__ cursor, int* __restrict__ csr, int n) {
    int e = blockIdx.x * blockDim.x + threadIdx.x;
    if (e < n) {
        int d = dst[e];
        int p = atomicAdd(&cursor[d], 1);
        csr[p] = src[e];
    }
}

// ---------------- GEMM: out[row] = dinv[row] * (A[row,:K] @ W[:K,:256]) ----------------
// 64x64 tile, 16x16 threads, 4x4 register tile, BK=16.

__global__ __launch_bounds__(256) void k_gemm(const float* __restrict__ A,
                                              const float* __restrict__ W,
                                              const float* __restrict__ dinv,
                                              float* __restrict__ out,
                                              int M, int K) {
    __shared__ float As[16][68];   // [k][m], padded, rows 16B-aligned
    __shared__ float Ws[16][68];   // [k][n]
    const int tid = threadIdx.x;
    const int tx = tid & 15, ty = tid >> 4;
    const int bm = blockIdx.x * 64, bn = blockIdx.y * 64;
    float acc[4][4] = {};

    for (int kk = 0; kk < K; kk += 16) {
        {   // A tile: 64 rows x 16 k, transposed into As[k][m]
            int m  = tid >> 2;
            int k4 = (tid & 3) << 2;
            int row = bm + m;
            float4 v = make_float4(0.f, 0.f, 0.f, 0.f);
            if (row < M) v = *(const float4*)&A[(size_t)row * K + kk + k4];
            As[k4 + 0][m] = v.x; As[k4 + 1][m] = v.y;
            As[k4 + 2][m] = v.z; As[k4 + 3][m] = v.w;
        }
        {   // W tile: 16 k x 64 cols
            int k = tid >> 4;
            int j = (tid & 15) << 2;
            *(float4*)&Ws[k][j] = *(const float4*)&W[(size_t)(kk + k) * HID + bn + j];
        }
        __syncthreads();
#pragma unroll
        for (int k = 0; k < 16; ++k) {
            float4 a4 = *(const float4*)&As[k][ty << 2];
            float4 w4 = *(const float4*)&Ws[k][tx << 2];
            float av[4] = {a4.x, a4.y, a4.z, a4.w};
            float wv[4] = {w4.x, w4.y, w4.z, w4.w};
#pragma unroll
            for (int i = 0; i < 4; ++i)
#pragma unroll
                for (int j = 0; j < 4; ++j)
                    acc[i][j] = fmaf(av[i], wv[j], acc[i][j]);
        }
        __syncthreads();
    }
#pragma unroll
    for (int i = 0; i < 4; ++i) {
        int row = bm + (ty << 2) + i;
        if (row >= M) continue;
        float s = dinv[row];
        float4 o;
        o.x = s * acc[i][0]; o.y = s * acc[i][1];
        o.z = s * acc[i][2]; o.w = s * acc[i][3];
        *(float4*)&out[(size_t)row * HID + bn + (tx << 2)] = o;
    }
}

// ---------------- aggregation: a[d] = relu(dinv[d]*(hs[d] + sum_{e in in(d)} hs[src_e]) + b) --------
// one wave per node; lane covers 4 channels (float4)

__global__ __launch_bounds__(256) void k_aggregate(const float* __restrict__ hs,
                                                   const int* __restrict__ csr,
                                                   const int* __restrict__ offs,
                                                   const int* __restrict__ deg,
                                                   const float* __restrict__ dinv,
                                                   const float* __restrict__ bias,
                                                   float* __restrict__ out, int n) {
    int wid = threadIdx.x >> 6, lane = threadIdx.x & 63;
    int node = blockIdx.x * 4 + wid;
    if (node >= n) return;
    int c = lane << 2;
    const float4 self = *(const float4*)&hs[(size_t)node * HID + c];
    float ax = self.x, ay = self.y, az = self.z, aw = self.w;
    int s0 = offs[node], cnt = deg[node];
    for (int i = 0; i < cnt; ++i) {
        int s = csr[s0 + i];
        const float4 v = *(const float4*)&hs[(size_t)s * HID + c];
        ax += v.x; ay += v.y; az += v.z; aw += v.w;
    }
    float dv = dinv[node];
    const float4 bb = *(const float4*)&bias[c];
    float4 r;
    r.x = fmaxf(fmaf(dv, ax, bb.x), 0.f);
    r.y = fmaxf(fmaf(dv, ay, bb.y), 0.f);
    r.z = fmaxf(fmaf(dv, az, bb.z), 0.f);
    r.w = fmaxf(fmaf(dv, aw, bb.w), 0.f);
    *(float4*)&out[(size_t)node * HID + c] = r;
}

// ---------------- pooling: batch is sorted -> run-length accumulate, flush on change ----------

__global__ __launch_bounds__(256) void k_pool(const float* __restrict__ a,
                                              const int* __restrict__ batch,
                                              float* __restrict__ pooled,
                                              float* __restrict__ countsf, int n) {
    int wid = threadIdx.x >> 6, lane = threadIdx.x & 63;
    int wg = blockIdx.x * 4 + wid;
    int n0 = wg * 16;
    if (n0 >= n) return;
    int n1 = min(n0 + 16, n);
    int c = lane << 2;
    float ax = 0.f, ay = 0.f, az = 0.f, aw = 0.f;
    int gcur = -1; float run = 0.f;
    for (int nd = n0; nd < n1; ++nd) {
        int g = batch[nd];
        if (g != gcur) {
            if (gcur >= 0) {
                atomicAdd(&pooled[gcur * HID + c + 0], ax);
                atomicAdd(&pooled[gcur * HID + c + 1], ay);
                atomicAdd(&pooled[gcur * HID + c + 2], az);
                atomicAdd(&pooled[gcur * HID + c + 3], aw);
                if (lane == 0) atomicAdd(&countsf[gcur], run);
            }
            gcur = g; ax = ay = az = aw = 0.f; run = 0.f;
        }
        const float4 v = *(const float4*)&a[(size_t)nd * HID + c];
        ax += v.x; ay += v.y; az += v.z; aw += v.w;
        run += 1.f;
    }
    if (gcur >= 0) {
        atomicAdd(&pooled[gcur * HID + c + 0], ax);
        atomicAdd(&pooled[gcur * HID + c + 1], ay);
        atomicAdd(&pooled[gcur * HID + c + 2], az);
        atomicAdd(&pooled[gcur * HID + c + 3], aw);
        if (lane == 0) atomicAdd(&countsf[gcur], run);
    }
}

// ---------------- head MLP: one block per graph ----------------

__global__ __launch_bounds__(256) void k_mlp(const float* __restrict__ pooled,
                                             const float* __restrict__ countsf,
                                             const float* __restrict__ Wf1,
                                             const float* __restrict__ bf1,
                                             const float* __restrict__ Wf2,
                                             const float* __restrict__ bf2,
                                             float* __restrict__ out) {
    __shared__ float p[HID];
    __shared__ float z[HID];
    int g = blockIdx.x, t = threadIdx.x;
    float cnt = fmaxf(countsf[g], 1.0f);
    p[t] = pooled[g * HID + t] / cnt;
    __syncthreads();
    float accz = bf1[t];
    for (int k = 0; k < HID; ++k)
        accz = fmaf(p[k], Wf1[k * HID + t], accz);
    z[t] = fmaxf(accz, 0.f);
    __syncthreads();
    if (t < NCLS) {
        float o = bf2[t];
        for (int k = 0; k < HID; ++k)
            o = fmaf(z[k], Wf2[k * NCLS + t], o);
        // stable softplus: max(o,0) + log1p(exp(-|o|))
        float sp = fmaxf(o, 0.f) + log1pf(expf(-fabsf(o)));
        out[g * NCLS + t] = sp + 0.001f;
    }
}

// ---------------- launch ----------------

extern "C" void kernel_launch(void* const* d_in, const int* in_sizes, int n_in,
                              void* d_out, int out_size, void* d_ws, size_t ws_size,
                              hipStream_t stream) {
    const float* x     = (const float*)d_in[0];
    const int*   ei    = (const int*)d_in[1];
    const int*   batch = (const int*)d_in[2];
    const float* W1    = (const float*)d_in[3];
    const float* b1    = (const float*)d_in[4];
    const float* W2    = (const float*)d_in[5];
    const float* b2    = (const float*)d_in[6];
    const float* Wf1   = (const float*)d_in[7];
    const float* bf1   = (const float*)d_in[8];
    const float* Wf2   = (const float*)d_in[9];
    const float* bf2   = (const float*)d_in[10];
    float* out = (float*)d_out;

    const int* srcv = ei;        // edge_index[0,:]
    const int* dstv = ei + NE;   // edge_index[1,:]

    char* p = (char*)d_ws;
    auto take = [&](size_t bytes) -> char* {
        char* q = p; p += (bytes + 255) & ~(size_t)255; return q;
    };
    float* hs      = (float*)take((size_t)NN * HID * 4);
    float* abuf    = (float*)take((size_t)NN * HID * 4);
    int*   deg     = (int*)take((size_t)NN * 4);
    int*   offs    = (int*)take((size_t)NN * 4);
    int*   cursor  = (int*)take((size_t)NN * 4);
    int*   csr     = (int*)take((size_t)NE * 4);
    float* dinv    = (float*)take((size_t)NN * 4);
    int*   bsum    = (int*)take(128 * 4);
    int*   boff    = (int*)take(128 * 4);
    float* pooled  = (float*)take((size_t)NG * HID * 4);
    float* countsf = (float*)take((size_t)NG * 4);

    hipMemsetAsync(deg, 0, (size_t)NN * 4, stream);
    hipMemsetAsync(pooled, 0, (size_t)NG * HID * 4, stream);
    hipMemsetAsync(countsf, 0, (size_t)NG * 4, stream);

    const int NB = (NN + 1023) / 1024;  // 98 blocks

    k_deg<<<(NE + 255) / 256, 256, 0, stream>>>(dstv, deg, NE);
    k_dinv<<<(NN + 255) / 256, 256, 0, stream>>>(deg, dinv, NN);
    k_bsum<<<NB, 256, 0, stream>>>(deg, bsum, NN);
    k_scanb<<<1, 128, 0, stream>>>(bsum, boff, NB);
    k_offs<<<NB, 256, 0, stream>>>(deg, boff, offs, NN);
    hipMemcpyAsync(cursor, offs, (size_t)NN * 4, hipMemcpyDeviceToDevice, stream);
    k_fill<<<(NE + 255) / 256, 256, 0, stream>>>(srcv, dstv, cursor, csr, NE);

    dim3 gg((NN + 63) / 64, HID / 64);
    k_gemm<<<gg, 256, 0, stream>>>(x, W1, dinv, hs, NN, DIN);
    k_aggregate<<<(NN + 3) / 4, 256, 0, stream>>>(hs, csr, offs, deg, dinv, b1, abuf, NN);
    k_gemm<<<gg, 256, 0, stream>>>(abuf, W2, dinv, hs, NN, HID);
    k_aggregate<<<(NN + 3) / 4, 256, 0, stream>>>(hs, csr, offs, deg, dinv, b2, abuf, NN);

    int pool_waves  = (NN + 15) / 16;
    int pool_blocks = (pool_waves + 3) / 4;
    k_pool<<<pool_blocks, 256, 0, stream>>>(abuf, batch, pooled, countsf, NN);
    k_mlp<<<NG, 256, 0, stream>>>(pooled, countsf, Wf1, bf1, Wf2, bf2, out);
}

// Round 2
// 739.856 us; speedup vs baseline: 1.4122x; 1.4122x over previous
//
#include <hip/hip_runtime.h>
#include <math.h>

#define NN   100000
#define NE   1600000
#define DIN  128
#define HID  256
#define NG   64
#define NCLS 10

using bf16x8 = __attribute__((ext_vector_type(8))) short;
using f32x4  = __attribute__((ext_vector_type(4))) float;

static __device__ __forceinline__ unsigned short f2bf(float f) {
    unsigned u = __float_as_uint(f);
    u += 0x7fff + ((u >> 16) & 1);   // round-to-nearest-even
    return (unsigned short)(u >> 16);
}
static __device__ __forceinline__ float bf2f(unsigned short h) {
    return __uint_as_float(((unsigned)h) << 16);
}

// ---------------- graph preprocessing ----------------

__global__ void k_deg(const int* __restrict__ dst, int* __restrict__ deg, int n) {
    int e = blockIdx.x * blockDim.x + threadIdx.x;
    if (e < n) atomicAdd(&deg[dst[e]], 1);
}

__global__ void k_dinv(const int* __restrict__ deg, float* __restrict__ dinv, int n) {
    int i = blockIdx.x * blockDim.x + threadIdx.x;
    if (i < n) dinv[i] = rsqrtf((float)(deg[i] + 1));
}

__global__ void k_bsum(const int* __restrict__ deg, int* __restrict__ bsum, int n) {
    __shared__ int sd[256];
    int t = threadIdx.x;
    int base = blockIdx.x * 1024 + t * 4;
    int s = 0;
#pragma unroll
    for (int i = 0; i < 4; ++i)
        if (base + i < n) s += deg[base + i];
    sd[t] = s; __syncthreads();
    for (int off = 128; off > 0; off >>= 1) {
        if (t < off) sd[t] += sd[t + off];
        __syncthreads();
    }
    if (t == 0) bsum[blockIdx.x] = sd[0];
}

__global__ void k_scanb(const int* __restrict__ bsum, int* __restrict__ boff, int nb) {
    __shared__ int tmp[128];
    int t = threadIdx.x;
    int v = (t < nb) ? bsum[t] : 0;
    tmp[t] = v; __syncthreads();
    for (int off = 1; off < 128; off <<= 1) {
        int u = (t >= off) ? tmp[t - off] : 0;
        __syncthreads();
        tmp[t] += u;
        __syncthreads();
    }
    if (t < nb) boff[t] = tmp[t] - v;
}

__global__ void k_offs(const int* __restrict__ deg, const int* __restrict__ boff,
                       int* __restrict__ offs, int n) {
    __shared__ int ts[256];
    int t = threadIdx.x;
    int base = blockIdx.x * 1024 + t * 4;
    int v[4]; int s = 0;
#pragma unroll
    for (int i = 0; i < 4; ++i) { v[i] = (base + i < n) ? deg[base + i] : 0; s += v[i]; }
    ts[t] = s; __syncthreads();
    int mine = s;
    for (int off = 1; off < 256; off <<= 1) {
        int u = (t >= off) ? ts[t - off] : 0;
        __syncthreads();
        ts[t] += u;
        __syncthreads();
    }
    int run = ts[t] - mine + boff[blockIdx.x];
#pragma unroll
    for (int i = 0; i < 4; ++i) {
        if (base + i < n) { offs[base + i] = run; run += v[i]; }
    }
}

__global__ void k_fill(const int* __restrict__ src, const int* __restrict__ dst,
                       int* __restrict__ cursor, int* __restrict__ csr, int n) {
    int e = blockIdx.x * blockDim.x + threadIdx.x;
    if (e < n) {
        int d = dst[e];
        int p = atomicAdd(&cursor[d], 1);
        csr[p] = src[e];
    }
}

// ---------------- casts ----------------

// x [NN*DIN] f32 -> bf16, 4 elems/thread
__global__ void k_cast_x(const float* __restrict__ x, unsigned short* __restrict__ xb, int n4) {
    int i = blockIdx.x * blockDim.x + threadIdx.x;
    if (i >= n4) return;
    const float4 v = *(const float4*)&x[i * 4];
    ushort4 o;
    o.x = f2bf(v.x); o.y = f2bf(v.y); o.z = f2bf(v.z); o.w = f2bf(v.w);
    *(ushort4*)&xb[i * 4] = o;
}

// W [K][256] f32 -> Wt [256][K] bf16 (transpose)
__global__ void k_cast_wt(const float* __restrict__ W, unsigned short* __restrict__ Wt, int K) {
    int i = blockIdx.x * blockDim.x + threadIdx.x;
    if (i >= K * HID) return;
    int k = i >> 8;          // HID == 256
    int nc = i & 255;
    Wt[nc * K + k] = f2bf(W[i]);
}

// ---------------- MFMA GEMM: out[row] = bf16(dinv[row] * (A[row,:K] @ W[:K,:256])) ------------
// A bf16 [M][K], Wt bf16 [256][K] (W transposed). 128x128 tile, 4 waves (2x2),
// each wave 64x64 = 4x4 fragments of 16x16x32 bf16 MFMA. BK=32.

__global__ __launch_bounds__(256) void k_gemm_mfma(const unsigned short* __restrict__ A,
                                                   const unsigned short* __restrict__ Wt,
                                                   const float* __restrict__ dinv,
                                                   unsigned short* __restrict__ out,
                                                   int M, int K) {
    __shared__ unsigned short As[128 * 40];  // row stride 40 bf16 = 80B (2-way bank alias only)
    __shared__ unsigned short Bs[128 * 40];
    const int t = threadIdx.x;
    const int lane = t & 63;
    const int wid = t >> 6;
    const int wr = wid >> 1, wc = wid & 1;
    const int bm = blockIdx.x * 128, bn = blockIdx.y * 128;
    const int lr = lane & 15;
    const int ko = (lane >> 4) << 3;   // k offset 0/8/16/24

    f32x4 acc[4][4] = {};

    const int r = t >> 2;             // staging row 0..63
    const int kq = (t & 3) << 3;      // staging k offset 0/8/16/24

    for (int kk = 0; kk < K; kk += 32) {
#pragma unroll
        for (int h = 0; h < 128; h += 64) {
            int row = bm + r + h;
            int4 v = make_int4(0, 0, 0, 0);
            if (row < M) v = *(const int4*)&A[(size_t)row * K + kk + kq];
            *(int4*)&As[(r + h) * 40 + kq] = v;
        }
#pragma unroll
        for (int h = 0; h < 128; h += 64) {
            int nrow = bn + r + h;   // always < 256
            int4 v = *(const int4*)&Wt[(size_t)nrow * K + kk + kq];
            *(int4*)&Bs[(r + h) * 40 + kq] = v;
        }
        __syncthreads();
        bf16x8 af[4], bfr[4];
#pragma unroll
        for (int mf = 0; mf < 4; ++mf)
            af[mf] = *(const bf16x8*)&As[(wr * 64 + mf * 16 + lr) * 40 + ko];
#pragma unroll
        for (int nf = 0; nf < 4; ++nf)
            bfr[nf] = *(const bf16x8*)&Bs[(wc * 64 + nf * 16 + lr) * 40 + ko];
#pragma unroll
        for (int mf = 0; mf < 4; ++mf)
#pragma unroll
            for (int nf = 0; nf < 4; ++nf)
                acc[mf][nf] = __builtin_amdgcn_mfma_f32_16x16x32_bf16(af[mf], bfr[nf], acc[mf][nf], 0, 0, 0);
        __syncthreads();
    }

#pragma unroll
    for (int mf = 0; mf < 4; ++mf) {
#pragma unroll
        for (int b = 0; b < 4; ++b) {
            int row = bm + wr * 64 + mf * 16 + (lane >> 4) * 4 + b;
            if (row >= M) continue;
            float dv = dinv[row];
#pragma unroll
            for (int nf = 0; nf < 4; ++nf) {
                int col = bn + wc * 64 + nf * 16 + lr;
                out[(size_t)row * HID + col] = f2bf(dv * acc[mf][nf][b]);
            }
        }
    }
}

// ---------------- aggregation (bf16 in/out): a[d] = relu(dinv[d]*(hs[d] + sum hs[src]) + b) ---

__global__ __launch_bounds__(256) void k_aggregate(const unsigned short* __restrict__ hs,
                                                   const int* __restrict__ csr,
                                                   const int* __restrict__ offs,
                                                   const int* __restrict__ deg,
                                                   const float* __restrict__ dinv,
                                                   const float* __restrict__ bias,
                                                   unsigned short* __restrict__ out, int n) {
    int wid = threadIdx.x >> 6, lane = threadIdx.x & 63;
    int node = blockIdx.x * 4 + wid;
    if (node >= n) return;
    int c = lane << 2;
    const ushort4 self = *(const ushort4*)&hs[(size_t)node * HID + c];
    float ax = bf2f(self.x), ay = bf2f(self.y), az = bf2f(self.z), aw = bf2f(self.w);
    int s0 = offs[node], cnt = deg[node];
    for (int i = 0; i < cnt; ++i) {
        int s = csr[s0 + i];
        const ushort4 v = *(const ushort4*)&hs[(size_t)s * HID + c];
        ax += bf2f(v.x); ay += bf2f(v.y); az += bf2f(v.z); aw += bf2f(v.w);
    }
    float dv = dinv[node];
    const float4 bb = *(const float4*)&bias[c];
    ushort4 r;
    r.x = f2bf(fmaxf(fmaf(dv, ax, bb.x), 0.f));
    r.y = f2bf(fmaxf(fmaf(dv, ay, bb.y), 0.f));
    r.z = f2bf(fmaxf(fmaf(dv, az, bb.z), 0.f));
    r.w = f2bf(fmaxf(fmaf(dv, aw, bb.w), 0.f));
    *(ushort4*)&out[(size_t)node * HID + c] = r;
}

// ---------------- pooling (bf16 input): batch sorted -> run-length, flush on change -----------

__global__ __launch_bounds__(256) void k_pool(const unsigned short* __restrict__ a,
                                              const int* __restrict__ batch,
                                              float* __restrict__ pooled,
                                              float* __restrict__ countsf, int n) {
    int wid = threadIdx.x >> 6, lane = threadIdx.x & 63;
    int wg = blockIdx.x * 4 + wid;
    int n0 = wg * 16;
    if (n0 >= n) return;
    int n1 = min(n0 + 16, n);
    int c = lane << 2;
    float ax = 0.f, ay = 0.f, az = 0.f, aw = 0.f;
    int gcur = -1; float run = 0.f;
    for (int nd = n0; nd < n1; ++nd) {
        int g = batch[nd];
        if (g != gcur) {
            if (gcur >= 0) {
                atomicAdd(&pooled[gcur * HID + c + 0], ax);
                atomicAdd(&pooled[gcur * HID + c + 1], ay);
                atomicAdd(&pooled[gcur * HID + c + 2], az);
                atomicAdd(&pooled[gcur * HID + c + 3], aw);
                if (lane == 0) atomicAdd(&countsf[gcur], run);
            }
            gcur = g; ax = ay = az = aw = 0.f; run = 0.f;
        }
        const ushort4 v = *(const ushort4*)&a[(size_t)nd * HID + c];
        ax += bf2f(v.x); ay += bf2f(v.y); az += bf2f(v.z); aw += bf2f(v.w);
        run += 1.f;
    }
    if (gcur >= 0) {
        atomicAdd(&pooled[gcur * HID + c + 0], ax);
        atomicAdd(&pooled[gcur * HID + c + 1], ay);
        atomicAdd(&pooled[gcur * HID + c + 2], az);
        atomicAdd(&pooled[gcur * HID + c + 3], aw);
        if (lane == 0) atomicAdd(&countsf[gcur], run);
    }
}

// ---------------- head MLP: one block per graph ----------------

__global__ __launch_bounds__(256) void k_mlp(const float* __restrict__ pooled,
                                             const float* __restrict__ countsf,
                                             const float* __restrict__ Wf1,
                                             const float* __restrict__ bf1,
                                             const float* __restrict__ Wf2,
                                             const float* __restrict__ bf2,
                                             float* __restrict__ out) {
    __shared__ float p[HID];
    __shared__ float z[HID];
    int g = blockIdx.x, t = threadIdx.x;
    float cnt = fmaxf(countsf[g], 1.0f);
    p[t] = pooled[g * HID + t] / cnt;
    __syncthreads();
    float accz = bf1[t];
    for (int k = 0; k < HID; ++k)
        accz = fmaf(p[k], Wf1[k * HID + t], accz);
    z[t] = fmaxf(accz, 0.f);
    __syncthreads();
    if (t < NCLS) {
        float o = bf2[t];
        for (int k = 0; k < HID; ++k)
            o = fmaf(z[k], Wf2[k * NCLS + t], o);
        float sp = fmaxf(o, 0.f) + log1pf(expf(-fabsf(o)));
        out[g * NCLS + t] = sp + 0.001f;
    }
}

// ---------------- launch ----------------

extern "C" void kernel_launch(void* const* d_in, const int* in_sizes, int n_in,
                              void* d_out, int out_size, void* d_ws, size_t ws_size,
                              hipStream_t stream) {
    const float* x     = (const float*)d_in[0];
    const int*   ei    = (const int*)d_in[1];
    const int*   batch = (const int*)d_in[2];
    const float* W1    = (const float*)d_in[3];
    const float* b1    = (const float*)d_in[4];
    const float* W2    = (const float*)d_in[5];
    const float* b2    = (const float*)d_in[6];
    const float* Wf1   = (const float*)d_in[7];
    const float* bf1   = (const float*)d_in[8];
    const float* Wf2   = (const float*)d_in[9];
    const float* bf2   = (const float*)d_in[10];
    float* out = (float*)d_out;

    const int* srcv = ei;
    const int* dstv = ei + NE;

    char* p = (char*)d_ws;
    auto take = [&](size_t bytes) -> char* {
        char* q = p; p += (bytes + 255) & ~(size_t)255; return q;
    };
    // big bf16 buffers (reused across stages)
    unsigned short* bufA = (unsigned short*)take((size_t)NN * HID * 2); // xb (25.6MB used) then hs2
    unsigned short* bufB = (unsigned short*)take((size_t)NN * HID * 2); // hs1 then abuf2
    unsigned short* bufC = (unsigned short*)take((size_t)NN * HID * 2); // abuf1
    unsigned short* wt1  = (unsigned short*)take((size_t)DIN * HID * 2);
    unsigned short* wt2  = (unsigned short*)take((size_t)HID * HID * 2);
    int*   deg     = (int*)take((size_t)NN * 4);
    int*   offs    = (int*)take((size_t)NN * 4);
    int*   cursor  = (int*)take((size_t)NN * 4);
    int*   csr     = (int*)take((size_t)NE * 4);
    float* dinv    = (float*)take((size_t)NN * 4);
    int*   bsum    = (int*)take(128 * 4);
    int*   boff    = (int*)take(128 * 4);
    float* pooled  = (float*)take((size_t)NG * HID * 4);
    float* countsf = (float*)take((size_t)NG * 4);

    hipMemsetAsync(deg, 0, (size_t)NN * 4, stream);
    hipMemsetAsync(pooled, 0, (size_t)NG * HID * 4, stream);
    hipMemsetAsync(countsf, 0, (size_t)NG * 4, stream);

    const int NB = (NN + 1023) / 1024;

    k_deg<<<(NE + 255) / 256, 256, 0, stream>>>(dstv, deg, NE);
    k_dinv<<<(NN + 255) / 256, 256, 0, stream>>>(deg, dinv, NN);
    k_bsum<<<NB, 256, 0, stream>>>(deg, bsum, NN);
    k_scanb<<<1, 128, 0, stream>>>(bsum, boff, NB);
    k_offs<<<NB, 256, 0, stream>>>(deg, boff, offs, NN);
    hipMemcpyAsync(cursor, offs, (size_t)NN * 4, hipMemcpyDeviceToDevice, stream);
    k_fill<<<(NE + 255) / 256, 256, 0, stream>>>(srcv, dstv, cursor, csr, NE);

    // casts
    k_cast_x<<<(NN * DIN / 4 + 255) / 256, 256, 0, stream>>>(x, bufA, NN * DIN / 4);
    k_cast_wt<<<(DIN * HID + 255) / 256, 256, 0, stream>>>(W1, wt1, DIN);
    k_cast_wt<<<(HID * HID + 255) / 256, 256, 0, stream>>>(W2, wt2, HID);

    dim3 gg((NN + 127) / 128, HID / 128);
    // layer 1
    k_gemm_mfma<<<gg, 256, 0, stream>>>(bufA, wt1, dinv, bufB, NN, DIN);
    k_aggregate<<<(NN + 3) / 4, 256, 0, stream>>>(bufB, csr, offs, deg, dinv, b1, bufC, NN);
    // layer 2
    k_gemm_mfma<<<gg, 256, 0, stream>>>(bufC, wt2, dinv, bufA, NN, HID);
    k_aggregate<<<(NN + 3) / 4, 256, 0, stream>>>(bufA, csr, offs, deg, dinv, b2, bufB, NN);

    int pool_waves  = (NN + 15) / 16;
    int pool_blocks = (pool_waves + 3) / 4;
    k_pool<<<pool_blocks, 256, 0, stream>>>(bufB, batch, pooled, countsf, NN);
    k_mlp<<<NG, 256, 0, stream>>>(pooled, countsf, Wf1, bf1, Wf2, bf2, out);
}

// Round 3
// 579.310 us; speedup vs baseline: 1.8035x; 1.2771x over previous
//
#include <hip/hip_runtime.h>
#include <math.h>

#define NN   100000
#define NE   1600000
#define DIN  128
#define HID  256
#define NG   64
#define NCLS 10

using bf16x8 = __attribute__((ext_vector_type(8))) short;
using f32x4  = __attribute__((ext_vector_type(4))) float;

static __device__ __forceinline__ unsigned short f2bf(float f) {
    unsigned u = __float_as_uint(f);
    u += 0x7fff + ((u >> 16) & 1);   // round-to-nearest-even
    return (unsigned short)(u >> 16);
}
static __device__ __forceinline__ float bf2f(unsigned short h) {
    return __uint_as_float(((unsigned)h) << 16);
}

// ---------------- graph preprocessing ----------------

__global__ void k_deg(const int* __restrict__ dst, int* __restrict__ deg, int n) {
    int e = blockIdx.x * blockDim.x + threadIdx.x;
    if (e < n) atomicAdd(&deg[dst[e]], 1);
}

__global__ void k_dinv(const int* __restrict__ deg, float* __restrict__ dinv, int n) {
    int i = blockIdx.x * blockDim.x + threadIdx.x;
    if (i < n) dinv[i] = rsqrtf((float)(deg[i] + 1));
}

__global__ void k_bsum(const int* __restrict__ deg, int* __restrict__ bsum, int n) {
    __shared__ int sd[256];
    int t = threadIdx.x;
    int base = blockIdx.x * 1024 + t * 4;
    int s = 0;
#pragma unroll
    for (int i = 0; i < 4; ++i)
        if (base + i < n) s += deg[base + i];
    sd[t] = s; __syncthreads();
    for (int off = 128; off > 0; off >>= 1) {
        if (t < off) sd[t] += sd[t + off];
        __syncthreads();
    }
    if (t == 0) bsum[blockIdx.x] = sd[0];
}

__global__ void k_scanb(const int* __restrict__ bsum, int* __restrict__ boff, int nb) {
    __shared__ int tmp[128];
    int t = threadIdx.x;
    int v = (t < nb) ? bsum[t] : 0;
    tmp[t] = v; __syncthreads();
    for (int off = 1; off < 128; off <<= 1) {
        int u = (t >= off) ? tmp[t - off] : 0;
        __syncthreads();
        tmp[t] += u;
        __syncthreads();
    }
    if (t < nb) boff[t] = tmp[t] - v;
}

__global__ void k_offs(const int* __restrict__ deg, const int* __restrict__ boff,
                       int* __restrict__ offs, int n) {
    __shared__ int ts[256];
    int t = threadIdx.x;
    int base = blockIdx.x * 1024 + t * 4;
    int v[4]; int s = 0;
#pragma unroll
    for (int i = 0; i < 4; ++i) { v[i] = (base + i < n) ? deg[base + i] : 0; s += v[i]; }
    ts[t] = s; __syncthreads();
    int mine = s;
    for (int off = 1; off < 256; off <<= 1) {
        int u = (t >= off) ? ts[t - off] : 0;
        __syncthreads();
        ts[t] += u;
        __syncthreads();
    }
    int run = ts[t] - mine + boff[blockIdx.x];
#pragma unroll
    for (int i = 0; i < 4; ++i) {
        if (base + i < n) { offs[base + i] = run; run += v[i]; }
    }
}

__global__ void k_fill(const int* __restrict__ src, const int* __restrict__ dst,
                       int* __restrict__ cursor, int* __restrict__ csr, int n) {
    int e = blockIdx.x * blockDim.x + threadIdx.x;
    if (e < n) {
        int d = dst[e];
        int p = atomicAdd(&cursor[d], 1);
        csr[p] = src[e];
    }
}

// ---------------- casts ----------------

// xs = bf16(dinv[row] * x[row]) : [NN][128]
__global__ void k_cast_scale_x(const float* __restrict__ x, const float* __restrict__ dinv,
                               unsigned short* __restrict__ xb, int n4) {
    int i = blockIdx.x * blockDim.x + threadIdx.x;
    if (i >= n4) return;
    float dv = dinv[i >> 5];           // 32 quads per 128-ch row
    const float4 v = *(const float4*)&x[i * 4];
    ushort4 o;
    o.x = f2bf(v.x * dv); o.y = f2bf(v.y * dv);
    o.z = f2bf(v.z * dv); o.w = f2bf(v.w * dv);
    *(ushort4*)&xb[i * 4] = o;
}

// W [K][256] f32 -> Wt [256][K] bf16 (transpose)
__global__ void k_cast_wt(const float* __restrict__ W, unsigned short* __restrict__ Wt, int K) {
    int i = blockIdx.x * blockDim.x + threadIdx.x;
    if (i >= K * HID) return;
    int k = i >> 8;
    int nc = i & 255;
    Wt[nc * K + k] = f2bf(W[i]);
}

// ---------------- MFMA GEMM with fused epilogue ----------------
// MODE 1: out = bf16(dinv[row] * relu(acc + bias[col]))   (layer-1)
// MODE 2: out = bf16(relu(acc + bias[col]))               (layer-2)

template <int MODE>
__global__ __launch_bounds__(256) void k_gemm_mfma(const unsigned short* __restrict__ A,
                                                   const unsigned short* __restrict__ Wt,
                                                   const float* __restrict__ dinv,
                                                   const float* __restrict__ bias,
                                                   unsigned short* __restrict__ out,
                                                   int M, int K) {
    __shared__ unsigned short As[128 * 40];
    __shared__ unsigned short Bs[128 * 40];
    const int t = threadIdx.x;
    const int lane = t & 63;
    const int wid = t >> 6;
    const int wr = wid >> 1, wc = wid & 1;
    const int bm = blockIdx.x * 128, bn = blockIdx.y * 128;
    const int lr = lane & 15;
    const int ko = (lane >> 4) << 3;

    f32x4 acc[4][4] = {};

    const int r = t >> 2;
    const int kq = (t & 3) << 3;

    for (int kk = 0; kk < K; kk += 32) {
#pragma unroll
        for (int h = 0; h < 128; h += 64) {
            int row = bm + r + h;
            int4 v = make_int4(0, 0, 0, 0);
            if (row < M) v = *(const int4*)&A[(size_t)row * K + kk + kq];
            *(int4*)&As[(r + h) * 40 + kq] = v;
        }
#pragma unroll
        for (int h = 0; h < 128; h += 64) {
            int nrow = bn + r + h;
            int4 v = *(const int4*)&Wt[(size_t)nrow * K + kk + kq];
            *(int4*)&Bs[(r + h) * 40 + kq] = v;
        }
        __syncthreads();
        bf16x8 af[4], bfr[4];
#pragma unroll
        for (int mf = 0; mf < 4; ++mf)
            af[mf] = *(const bf16x8*)&As[(wr * 64 + mf * 16 + lr) * 40 + ko];
#pragma unroll
        for (int nf = 0; nf < 4; ++nf)
            bfr[nf] = *(const bf16x8*)&Bs[(wc * 64 + nf * 16 + lr) * 40 + ko];
#pragma unroll
        for (int mf = 0; mf < 4; ++mf)
#pragma unroll
            for (int nf = 0; nf < 4; ++nf)
                acc[mf][nf] = __builtin_amdgcn_mfma_f32_16x16x32_bf16(af[mf], bfr[nf], acc[mf][nf], 0, 0, 0);
        __syncthreads();
    }

#pragma unroll
    for (int mf = 0; mf < 4; ++mf) {
#pragma unroll
        for (int b = 0; b < 4; ++b) {
            int row = bm + wr * 64 + mf * 16 + (lane >> 4) * 4 + b;
            if (row >= M) continue;
            float dv = (MODE == 1) ? dinv[row] : 1.0f;
#pragma unroll
            for (int nf = 0; nf < 4; ++nf) {
                int col = bn + wc * 64 + nf * 16 + lr;
                float v = fmaxf(acc[mf][nf][b] + bias[col], 0.f);
                if (MODE == 1) v *= dv;
                out[(size_t)row * HID + col] = f2bf(v);
            }
        }
    }
}

// ---------------- aggregation, 256 channels, 4-edge MLP unroll ----------------
// out[d] = bf16(dinv[d] * (hs[d] + sum_{s in N(d)} hs[s]))

__global__ __launch_bounds__(256) void k_agg256(const unsigned short* __restrict__ hs,
                                                const int* __restrict__ csr,
                                                const int* __restrict__ offs,
                                                const int* __restrict__ deg,
                                                const float* __restrict__ dinv,
                                                unsigned short* __restrict__ out, int n) {
    int wid = threadIdx.x >> 6, lane = threadIdx.x & 63;
    int node = blockIdx.x * 4 + wid;
    if (node >= n) return;
    int c = lane << 2;
    const ushort4 self = *(const ushort4*)&hs[(size_t)node * HID + c];
    float a0 = bf2f(self.x), a1 = bf2f(self.y), a2 = bf2f(self.z), a3 = bf2f(self.w);
    int s0 = offs[node], cnt = deg[node];
    for (int base = 0; base < cnt; base += 64) {
        int nb = min(64, cnt - base);
        int idx = (lane < nb) ? csr[s0 + base + lane] : 0;
        int i = 0;
        for (; i + 4 <= nb; i += 4) {
            int j0 = __shfl(idx, i + 0);
            int j1 = __shfl(idx, i + 1);
            int j2 = __shfl(idx, i + 2);
            int j3 = __shfl(idx, i + 3);
            const ushort4 v0 = *(const ushort4*)&hs[(size_t)j0 * HID + c];
            const ushort4 v1 = *(const ushort4*)&hs[(size_t)j1 * HID + c];
            const ushort4 v2 = *(const ushort4*)&hs[(size_t)j2 * HID + c];
            const ushort4 v3 = *(const ushort4*)&hs[(size_t)j3 * HID + c];
            a0 += bf2f(v0.x) + bf2f(v1.x) + bf2f(v2.x) + bf2f(v3.x);
            a1 += bf2f(v0.y) + bf2f(v1.y) + bf2f(v2.y) + bf2f(v3.y);
            a2 += bf2f(v0.z) + bf2f(v1.z) + bf2f(v2.z) + bf2f(v3.z);
            a3 += bf2f(v0.w) + bf2f(v1.w) + bf2f(v2.w) + bf2f(v3.w);
        }
        for (; i < nb; ++i) {
            int j = __shfl(idx, i);
            const ushort4 v = *(const ushort4*)&hs[(size_t)j * HID + c];
            a0 += bf2f(v.x); a1 += bf2f(v.y); a2 += bf2f(v.z); a3 += bf2f(v.w);
        }
    }
    float dv = dinv[node];
    ushort4 r;
    r.x = f2bf(dv * a0); r.y = f2bf(dv * a1);
    r.z = f2bf(dv * a2); r.w = f2bf(dv * a3);
    *(ushort4*)&out[(size_t)node * HID + c] = r;
}

// ---------------- aggregation, 128 channels (pre-GEMM1) ----------------
// Half-wave per edge: lanes 0-31 and 32-63 process different edges of the
// same node; each half covers all 128 channels (32 lanes x ushort4).
// out[d] = bf16(dinv[d] * (xs[d] + sum_{s in N(d)} xs[s]))

__global__ __launch_bounds__(256) void k_agg128(const unsigned short* __restrict__ xs,
                                                const int* __restrict__ csr,
                                                const int* __restrict__ offs,
                                                const int* __restrict__ deg,
                                                const float* __restrict__ dinv,
                                                unsigned short* __restrict__ out, int n) {
    int wid = threadIdx.x >> 6, lane = threadIdx.x & 63;
    int node = blockIdx.x * 4 + wid;
    if (node >= n) return;
    int half = lane >> 5, l32 = lane & 31;
    int c = l32 << 2;
    float a0 = 0.f, a1 = 0.f, a2 = 0.f, a3 = 0.f;
    if (half == 0) {
        const ushort4 s = *(const ushort4*)&xs[(size_t)node * DIN + c];
        a0 = bf2f(s.x); a1 = bf2f(s.y); a2 = bf2f(s.z); a3 = bf2f(s.w);
    }
    int s0 = offs[node], cnt = deg[node];
    for (int base = 0; base < cnt; base += 64) {
        int nb = min(64, cnt - base);
        int idx = (lane < nb) ? csr[s0 + base + lane] : 0;
        for (int i = 0; i < nb; i += 4) {
            int e0 = i + half;         // edges i, i+1 across the two halves
            int e1 = i + 2 + half;     // edges i+2, i+3
            int j0 = __shfl(idx, e0 < nb ? e0 : 0);
            int j1 = __shfl(idx, e1 < nb ? e1 : 0);
            if (e0 < nb) {
                const ushort4 v = *(const ushort4*)&xs[(size_t)j0 * DIN + c];
                a0 += bf2f(v.x); a1 += bf2f(v.y); a2 += bf2f(v.z); a3 += bf2f(v.w);
            }
            if (e1 < nb) {
                const ushort4 v = *(const ushort4*)&xs[(size_t)j1 * DIN + c];
                a0 += bf2f(v.x); a1 += bf2f(v.y); a2 += bf2f(v.z); a3 += bf2f(v.w);
            }
        }
    }
    a0 += __shfl_xor(a0, 32);
    a1 += __shfl_xor(a1, 32);
    a2 += __shfl_xor(a2, 32);
    a3 += __shfl_xor(a3, 32);
    if (half == 0) {
        float dv = dinv[node];
        ushort4 r;
        r.x = f2bf(dv * a0); r.y = f2bf(dv * a1);
        r.z = f2bf(dv * a2); r.w = f2bf(dv * a3);
        *(ushort4*)&out[(size_t)node * DIN + c] = r;
    }
}

// ---------------- pooling (bf16 input) ----------------

__global__ __launch_bounds__(256) void k_pool(const unsigned short* __restrict__ a,
                                              const int* __restrict__ batch,
                                              float* __restrict__ pooled,
                                              float* __restrict__ countsf, int n) {
    int wid = threadIdx.x >> 6, lane = threadIdx.x & 63;
    int wg = blockIdx.x * 4 + wid;
    int n0 = wg * 16;
    if (n0 >= n) return;
    int n1 = min(n0 + 16, n);
    int c = lane << 2;
    float ax = 0.f, ay = 0.f, az = 0.f, aw = 0.f;
    int gcur = -1; float run = 0.f;
    for (int nd = n0; nd < n1; ++nd) {
        int g = batch[nd];
        if (g != gcur) {
            if (gcur >= 0) {
                atomicAdd(&pooled[gcur * HID + c + 0], ax);
                atomicAdd(&pooled[gcur * HID + c + 1], ay);
                atomicAdd(&pooled[gcur * HID + c + 2], az);
                atomicAdd(&pooled[gcur * HID + c + 3], aw);
                if (lane == 0) atomicAdd(&countsf[gcur], run);
            }
            gcur = g; ax = ay = az = aw = 0.f; run = 0.f;
        }
        const ushort4 v = *(const ushort4*)&a[(size_t)nd * HID + c];
        ax += bf2f(v.x); ay += bf2f(v.y); az += bf2f(v.z); aw += bf2f(v.w);
        run += 1.f;
    }
    if (gcur >= 0) {
        atomicAdd(&pooled[gcur * HID + c + 0], ax);
        atomicAdd(&pooled[gcur * HID + c + 1], ay);
        atomicAdd(&pooled[gcur * HID + c + 2], az);
        atomicAdd(&pooled[gcur * HID + c + 3], aw);
        if (lane == 0) atomicAdd(&countsf[gcur], run);
    }
}

// ---------------- head MLP ----------------

__global__ __launch_bounds__(256) void k_mlp(const float* __restrict__ pooled,
                                             const float* __restrict__ countsf,
                                             const float* __restrict__ Wf1,
                                             const float* __restrict__ bf1,
                                             const float* __restrict__ Wf2,
                                             const float* __restrict__ bf2,
                                             float* __restrict__ out) {
    __shared__ float p[HID];
    __shared__ float z[HID];
    int g = blockIdx.x, t = threadIdx.x;
    float cnt = fmaxf(countsf[g], 1.0f);
    p[t] = pooled[g * HID + t] / cnt;
    __syncthreads();
    float accz = bf1[t];
    for (int k = 0; k < HID; ++k)
        accz = fmaf(p[k], Wf1[k * HID + t], accz);
    z[t] = fmaxf(accz, 0.f);
    __syncthreads();
    if (t < NCLS) {
        float o = bf2[t];
        for (int k = 0; k < HID; ++k)
            o = fmaf(z[k], Wf2[k * NCLS + t], o);
        float sp = fmaxf(o, 0.f) + log1pf(expf(-fabsf(o)));
        out[g * NCLS + t] = sp + 0.001f;
    }
}

// ---------------- launch ----------------

extern "C" void kernel_launch(void* const* d_in, const int* in_sizes, int n_in,
                              void* d_out, int out_size, void* d_ws, size_t ws_size,
                              hipStream_t stream) {
    const float* x     = (const float*)d_in[0];
    const int*   ei    = (const int*)d_in[1];
    const int*   batch = (const int*)d_in[2];
    const float* W1    = (const float*)d_in[3];
    const float* b1    = (const float*)d_in[4];
    const float* W2    = (const float*)d_in[5];
    const float* b2    = (const float*)d_in[6];
    const float* Wf1   = (const float*)d_in[7];
    const float* bf1   = (const float*)d_in[8];
    const float* Wf2   = (const float*)d_in[9];
    const float* bf2   = (const float*)d_in[10];
    float* out = (float*)d_out;

    const int* srcv = ei;
    const int* dstv = ei + NE;

    char* p = (char*)d_ws;
    auto take = [&](size_t bytes) -> char* {
        char* q = p; p += (bytes + 255) & ~(size_t)255; return q;
    };
    // big0: xs [NN*128] + xa [NN*128] packed; later reused (whole) as r [NN*256]
    unsigned short* big0 = (unsigned short*)take((size_t)NN * HID * 2);
    // big1: h [NN*256]; later reused as out2 [NN*256]
    unsigned short* big1 = (unsigned short*)take((size_t)NN * HID * 2);
    unsigned short* xs = big0;
    unsigned short* xa = big0 + (size_t)NN * DIN;
    unsigned short* hB = big1;
    unsigned short* rB = big0;
    unsigned short* o2 = big1;
    unsigned short* wt1  = (unsigned short*)take((size_t)DIN * HID * 2);
    unsigned short* wt2  = (unsigned short*)take((size_t)HID * HID * 2);
    int*   deg     = (int*)take((size_t)NN * 4);
    int*   offs    = (int*)take((size_t)NN * 4);
    int*   cursor  = (int*)take((size_t)NN * 4);
    int*   csr     = (int*)take((size_t)NE * 4);
    float* dinv    = (float*)take((size_t)NN * 4);
    int*   bsum    = (int*)take(128 * 4);
    int*   boff    = (int*)take(128 * 4);
    float* pooled  = (float*)take((size_t)NG * HID * 4);
    float* countsf = (float*)take((size_t)NG * 4);

    hipMemsetAsync(deg, 0, (size_t)NN * 4, stream);
    hipMemsetAsync(pooled, 0, (size_t)NG * HID * 4, stream);
    hipMemsetAsync(countsf, 0, (size_t)NG * 4, stream);

    const int NB = (NN + 1023) / 1024;

    k_deg<<<(NE + 255) / 256, 256, 0, stream>>>(dstv, deg, NE);
    k_dinv<<<(NN + 255) / 256, 256, 0, stream>>>(deg, dinv, NN);
    k_bsum<<<NB, 256, 0, stream>>>(deg, bsum, NN);
    k_scanb<<<1, 128, 0, stream>>>(bsum, boff, NB);
    k_offs<<<NB, 256, 0, stream>>>(deg, boff, offs, NN);
    hipMemcpyAsync(cursor, offs, (size_t)NN * 4, hipMemcpyDeviceToDevice, stream);
    k_fill<<<(NE + 255) / 256, 256, 0, stream>>>(srcv, dstv, cursor, csr, NE);

    // casts (xs = dinv .* x, bf16)
    k_cast_scale_x<<<(NN * DIN / 4 + 255) / 256, 256, 0, stream>>>(x, dinv, xs, NN * DIN / 4);
    k_cast_wt<<<(DIN * HID + 255) / 256, 256, 0, stream>>>(W1, wt1, DIN);
    k_cast_wt<<<(HID * HID + 255) / 256, 256, 0, stream>>>(W2, wt2, HID);

    dim3 gg((NN + 127) / 128, HID / 128);
    // layer 1: xa = Ahat_n x  (128-ch gather), then h = dinv .* relu(xa@W1 + b1)
    k_agg128<<<(NN + 3) / 4, 256, 0, stream>>>(xs, csr, offs, deg, dinv, xa, NN);
    k_gemm_mfma<1><<<gg, 256, 0, stream>>>(xa, wt1, dinv, b1, hB, NN, DIN);
    // layer 2: r = dinv .* (h + gather(h)), then out2 = relu(r@W2 + b2)
    k_agg256<<<(NN + 3) / 4, 256, 0, stream>>>(hB, csr, offs, deg, dinv, rB, NN);
    k_gemm_mfma<2><<<gg, 256, 0, stream>>>(rB, wt2, dinv, b2, o2, NN, HID);

    int pool_waves  = (NN + 15) / 16;
    int pool_blocks = (pool_waves + 3) / 4;
    k_pool<<<pool_blocks, 256, 0, stream>>>(o2, batch, pooled, countsf, NN);
    k_mlp<<<NG, 256, 0, stream>>>(pooled, countsf, Wf1, bf1, Wf2, bf2, out);
}

// Round 4
// 469.841 us; speedup vs baseline: 2.2237x; 1.2330x over previous
//
#include <hip/hip_runtime.h>
#include <math.h>

#define NN   100000
#define NE   1600000
#define DIN  128
#define HID  256
#define NG   64
#define NCLS 10

// counting-sort CSR build parameters
#define NBLK 128          // edge-chunk blocks (NE/NBLK = 12500 exactly)
#define EPB  (NE / NBLK)
#define NBUK 512          // dst buckets
#define NPB  196          // nodes per bucket (512*196 = 100352 >= NN)

using bf16x8 = __attribute__((ext_vector_type(8))) short;
using f32x4  = __attribute__((ext_vector_type(4))) float;

static __device__ __forceinline__ unsigned short f2bf(float f) {
    unsigned u = __float_as_uint(f);
    u += 0x7fff + ((u >> 16) & 1);   // round-to-nearest-even
    return (unsigned short)(u >> 16);
}
static __device__ __forceinline__ float bf2f(unsigned short h) {
    return __uint_as_float(((unsigned)h) << 16);
}

// ---------------- graph preprocessing: bucketed counting sort ----------------

// Pass A: per-(block,bucket) histogram, bucket-major layout histg[bkt*NBLK + blk]
__global__ __launch_bounds__(256) void k_hist(const int* __restrict__ dst,
                                              int* __restrict__ histg) {
    __shared__ int h[NBUK];
    const int t = threadIdx.x;
    for (int i = t; i < NBUK; i += 256) h[i] = 0;
    __syncthreads();
    const int e0 = blockIdx.x * EPB, e1 = e0 + EPB;
    for (int e = e0 + t; e < e1; e += 256)
        atomicAdd(&h[(unsigned)dst[e] / NPB], 1);
    __syncthreads();
    for (int i = t; i < NBUK; i += 256)
        histg[i * NBLK + blockIdx.x] = h[i];
}

// exclusive scan of the 65536-entry histogram, in place (1 block, 1024 thr)
__global__ __launch_bounds__(1024) void k_scan64k(int* __restrict__ d) {
    __shared__ int ts[1024];
    const int t = threadIdx.x;
    const int base = t * 64;
    int s = 0;
    for (int i = 0; i < 64; ++i) s += d[base + i];
    ts[t] = s;
    __syncthreads();
    for (int off = 1; off < 1024; off <<= 1) {
        int u = (t >= off) ? ts[t - off] : 0;
        __syncthreads();
        ts[t] += u;
        __syncthreads();
    }
    int run = ts[t] - s;   // exclusive prefix of this chunk
    for (int i = 0; i < 64; ++i) {
        int v = d[base + i];
        d[base + i] = run;
        run += v;
    }
}

// Pass B: scatter (src,dst) pairs into bucket-sorted order
__global__ __launch_bounds__(256) void k_scatter(const int* __restrict__ src,
                                                 const int* __restrict__ dst,
                                                 const int* __restrict__ offg,
                                                 int2* __restrict__ pairs) {
    __shared__ int cur[NBUK];
    const int t = threadIdx.x;
    for (int i = t; i < NBUK; i += 256) cur[i] = offg[i * NBLK + blockIdx.x];
    __syncthreads();
    const int e0 = blockIdx.x * EPB, e1 = e0 + EPB;
    for (int e = e0 + t; e < e1; e += 256) {
        int d = dst[e];
        int b = (unsigned)d / NPB;
        int p = atomicAdd(&cur[b], 1);
        pairs[p] = make_int2(src[e], d);
    }
}

// Pass C: per-bucket local CSR build + deg + dinv + offs (all L2-local)
__global__ __launch_bounds__(256) void k_csr(const int2* __restrict__ pairs,
                                             const int* __restrict__ offg,
                                             int* __restrict__ csr,
                                             int* __restrict__ deg,
                                             float* __restrict__ dinv,
                                             int* __restrict__ offs) {
    __shared__ int cnt[NPB];
    __shared__ int loff[256];
    __shared__ int cur[NPB];
    const int b = blockIdx.x, t = threadIdx.x;
    const int s     = offg[b * NBLK];
    const int e_end = (b == NBUK - 1) ? NE : offg[(b + 1) * NBLK];
    const int nb0   = b * NPB;
    const int nnod  = min(NPB, NN - nb0);   // <=0 for tail bucket(s)
    if (t < NPB) cnt[t] = 0;
    __syncthreads();
    for (int e = s + t; e < e_end; e += 256)
        atomicAdd(&cnt[pairs[e].y - nb0], 1);
    __syncthreads();
    int v = (t < NPB) ? cnt[t] : 0;
    loff[t] = v;
    __syncthreads();
    for (int off = 1; off < 256; off <<= 1) {
        int u = (t >= off) ? loff[t - off] : 0;
        __syncthreads();
        loff[t] += u;
        __syncthreads();
    }
    int myoff = loff[t] - v;   // exclusive prefix
    __syncthreads();
    loff[t] = myoff;
    if (t < NPB) cur[t] = 0;
    __syncthreads();
    if (t < nnod) {
        int node = nb0 + t;
        int dg = cnt[t];
        deg[node]  = dg;
        dinv[node] = rsqrtf((float)(dg + 1));
        offs[node] = s + myoff;
    }
    for (int e = s + t; e < e_end; e += 256) {
        int2 pr = pairs[e];
        int li = pr.y - nb0;
        int p = atomicAdd(&cur[li], 1);
        csr[s + loff[li] + p] = pr.x;
    }
}

// ---------------- casts ----------------

// xs = bf16(dinv[row] * x[row]) : [NN][128]
__global__ void k_cast_scale_x(const float* __restrict__ x, const float* __restrict__ dinv,
                               unsigned short* __restrict__ xb, int n4) {
    int i = blockIdx.x * blockDim.x + threadIdx.x;
    if (i >= n4) return;
    float dv = dinv[i >> 5];
    const float4 v = *(const float4*)&x[i * 4];
    ushort4 o;
    o.x = f2bf(v.x * dv); o.y = f2bf(v.y * dv);
    o.z = f2bf(v.z * dv); o.w = f2bf(v.w * dv);
    *(ushort4*)&xb[i * 4] = o;
}

// W [K][256] f32 -> Wt [256][K] bf16 (transpose)
__global__ void k_cast_wt(const float* __restrict__ W, unsigned short* __restrict__ Wt, int K) {
    int i = blockIdx.x * blockDim.x + threadIdx.x;
    if (i >= K * HID) return;
    int k = i >> 8;
    int nc = i & 255;
    Wt[nc * K + k] = f2bf(W[i]);
}

// ---------------- MFMA GEMM with fused epilogue ----------------
// MODE 1: out = bf16(dinv[row] * relu(acc + bias[col]))
// MODE 2: out = bf16(relu(acc + bias[col]))

template <int MODE>
__global__ __launch_bounds__(256) void k_gemm_mfma(const unsigned short* __restrict__ A,
                                                   const unsigned short* __restrict__ Wt,
                                                   const float* __restrict__ dinv,
                                                   const float* __restrict__ bias,
                                                   unsigned short* __restrict__ out,
                                                   int M, int K) {
    __shared__ unsigned short As[128 * 40];
    __shared__ unsigned short Bs[128 * 40];
    const int t = threadIdx.x;
    const int lane = t & 63;
    const int wid = t >> 6;
    const int wr = wid >> 1, wc = wid & 1;
    const int bm = blockIdx.x * 128, bn = blockIdx.y * 128;
    const int lr = lane & 15;
    const int ko = (lane >> 4) << 3;

    f32x4 acc[4][4] = {};

    const int r = t >> 2;
    const int kq = (t & 3) << 3;

    for (int kk = 0; kk < K; kk += 32) {
#pragma unroll
        for (int h = 0; h < 128; h += 64) {
            int row = bm + r + h;
            int4 v = make_int4(0, 0, 0, 0);
            if (row < M) v = *(const int4*)&A[(size_t)row * K + kk + kq];
            *(int4*)&As[(r + h) * 40 + kq] = v;
        }
#pragma unroll
        for (int h = 0; h < 128; h += 64) {
            int nrow = bn + r + h;
            int4 v = *(const int4*)&Wt[(size_t)nrow * K + kk + kq];
            *(int4*)&Bs[(r + h) * 40 + kq] = v;
        }
        __syncthreads();
        bf16x8 af[4], bfr[4];
#pragma unroll
        for (int mf = 0; mf < 4; ++mf)
            af[mf] = *(const bf16x8*)&As[(wr * 64 + mf * 16 + lr) * 40 + ko];
#pragma unroll
        for (int nf = 0; nf < 4; ++nf)
            bfr[nf] = *(const bf16x8*)&Bs[(wc * 64 + nf * 16 + lr) * 40 + ko];
#pragma unroll
        for (int mf = 0; mf < 4; ++mf)
#pragma unroll
            for (int nf = 0; nf < 4; ++nf)
                acc[mf][nf] = __builtin_amdgcn_mfma_f32_16x16x32_bf16(af[mf], bfr[nf], acc[mf][nf], 0, 0, 0);
        __syncthreads();
    }

#pragma unroll
    for (int mf = 0; mf < 4; ++mf) {
#pragma unroll
        for (int b = 0; b < 4; ++b) {
            int row = bm + wr * 64 + mf * 16 + (lane >> 4) * 4 + b;
            if (row >= M) continue;
            float dv = (MODE == 1) ? dinv[row] : 1.0f;
#pragma unroll
            for (int nf = 0; nf < 4; ++nf) {
                int col = bn + wc * 64 + nf * 16 + lr;
                float v = fmaxf(acc[mf][nf][b] + bias[col], 0.f);
                if (MODE == 1) v *= dv;
                out[(size_t)row * HID + col] = f2bf(v);
            }
        }
    }
}

// ---------------- aggregation, 256 channels ----------------

__global__ __launch_bounds__(256) void k_agg256(const unsigned short* __restrict__ hs,
                                                const int* __restrict__ csr,
                                                const int* __restrict__ offs,
                                                const int* __restrict__ deg,
                                                const float* __restrict__ dinv,
                                                unsigned short* __restrict__ out, int n) {
    int wid = threadIdx.x >> 6, lane = threadIdx.x & 63;
    int node = blockIdx.x * 4 + wid;
    if (node >= n) return;
    int c = lane << 2;
    const ushort4 self = *(const ushort4*)&hs[(size_t)node * HID + c];
    float a0 = bf2f(self.x), a1 = bf2f(self.y), a2 = bf2f(self.z), a3 = bf2f(self.w);
    int s0 = offs[node], cnt = deg[node];
    for (int base = 0; base < cnt; base += 64) {
        int nb = min(64, cnt - base);
        int idx = (lane < nb) ? csr[s0 + base + lane] : 0;
        int i = 0;
        for (; i + 4 <= nb; i += 4) {
            int j0 = __shfl(idx, i + 0);
            int j1 = __shfl(idx, i + 1);
            int j2 = __shfl(idx, i + 2);
            int j3 = __shfl(idx, i + 3);
            const ushort4 v0 = *(const ushort4*)&hs[(size_t)j0 * HID + c];
            const ushort4 v1 = *(const ushort4*)&hs[(size_t)j1 * HID + c];
            const ushort4 v2 = *(const ushort4*)&hs[(size_t)j2 * HID + c];
            const ushort4 v3 = *(const ushort4*)&hs[(size_t)j3 * HID + c];
            a0 += bf2f(v0.x) + bf2f(v1.x) + bf2f(v2.x) + bf2f(v3.x);
            a1 += bf2f(v0.y) + bf2f(v1.y) + bf2f(v2.y) + bf2f(v3.y);
            a2 += bf2f(v0.z) + bf2f(v1.z) + bf2f(v2.z) + bf2f(v3.z);
            a3 += bf2f(v0.w) + bf2f(v1.w) + bf2f(v2.w) + bf2f(v3.w);
        }
        for (; i < nb; ++i) {
            int j = __shfl(idx, i);
            const ushort4 v = *(const ushort4*)&hs[(size_t)j * HID + c];
            a0 += bf2f(v.x); a1 += bf2f(v.y); a2 += bf2f(v.z); a3 += bf2f(v.w);
        }
    }
    float dv = dinv[node];
    ushort4 r;
    r.x = f2bf(dv * a0); r.y = f2bf(dv * a1);
    r.z = f2bf(dv * a2); r.w = f2bf(dv * a3);
    *(ushort4*)&out[(size_t)node * HID + c] = r;
}

// ---------------- aggregation, 128 channels (pre-GEMM1) ----------------

__global__ __launch_bounds__(256) void k_agg128(const unsigned short* __restrict__ xs,
                                                const int* __restrict__ csr,
                                                const int* __restrict__ offs,
                                                const int* __restrict__ deg,
                                                const float* __restrict__ dinv,
                                                unsigned short* __restrict__ out, int n) {
    int wid = threadIdx.x >> 6, lane = threadIdx.x & 63;
    int node = blockIdx.x * 4 + wid;
    if (node >= n) return;
    int half = lane >> 5, l32 = lane & 31;
    int c = l32 << 2;
    float a0 = 0.f, a1 = 0.f, a2 = 0.f, a3 = 0.f;
    if (half == 0) {
        const ushort4 s = *(const ushort4*)&xs[(size_t)node * DIN + c];
        a0 = bf2f(s.x); a1 = bf2f(s.y); a2 = bf2f(s.z); a3 = bf2f(s.w);
    }
    int s0 = offs[node], cnt = deg[node];
    for (int base = 0; base < cnt; base += 64) {
        int nb = min(64, cnt - base);
        int idx = (lane < nb) ? csr[s0 + base + lane] : 0;
        for (int i = 0; i < nb; i += 4) {
            int e0 = i + half;
            int e1 = i + 2 + half;
            int j0 = __shfl(idx, e0 < nb ? e0 : 0);
            int j1 = __shfl(idx, e1 < nb ? e1 : 0);
            if (e0 < nb) {
                const ushort4 v = *(const ushort4*)&xs[(size_t)j0 * DIN + c];
                a0 += bf2f(v.x); a1 += bf2f(v.y); a2 += bf2f(v.z); a3 += bf2f(v.w);
            }
            if (e1 < nb) {
                const ushort4 v = *(const ushort4*)&xs[(size_t)j1 * DIN + c];
                a0 += bf2f(v.x); a1 += bf2f(v.y); a2 += bf2f(v.z); a3 += bf2f(v.w);
            }
        }
    }
    a0 += __shfl_xor(a0, 32);
    a1 += __shfl_xor(a1, 32);
    a2 += __shfl_xor(a2, 32);
    a3 += __shfl_xor(a3, 32);
    if (half == 0) {
        float dv = dinv[node];
        ushort4 r;
        r.x = f2bf(dv * a0); r.y = f2bf(dv * a1);
        r.z = f2bf(dv * a2); r.w = f2bf(dv * a3);
        *(ushort4*)&out[(size_t)node * DIN + c] = r;
    }
}

// ---------------- pooling ----------------

__global__ __launch_bounds__(256) void k_pool(const unsigned short* __restrict__ a,
                                              const int* __restrict__ batch,
                                              float* __restrict__ pooled,
                                              float* __restrict__ countsf, int n) {
    int wid = threadIdx.x >> 6, lane = threadIdx.x & 63;
    int wg = blockIdx.x * 4 + wid;
    int n0 = wg * 16;
    if (n0 >= n) return;
    int n1 = min(n0 + 16, n);
    int c = lane << 2;
    float ax = 0.f, ay = 0.f, az = 0.f, aw = 0.f;
    int gcur = -1; float run = 0.f;
    for (int nd = n0; nd < n1; ++nd) {
        int g = batch[nd];
        if (g != gcur) {
            if (gcur >= 0) {
                atomicAdd(&pooled[gcur * HID + c + 0], ax);
                atomicAdd(&pooled[gcur * HID + c + 1], ay);
                atomicAdd(&pooled[gcur * HID + c + 2], az);
                atomicAdd(&pooled[gcur * HID + c + 3], aw);
                if (lane == 0) atomicAdd(&countsf[gcur], run);
            }
            gcur = g; ax = ay = az = aw = 0.f; run = 0.f;
        }
        const ushort4 v = *(const ushort4*)&a[(size_t)nd * HID + c];
        ax += bf2f(v.x); ay += bf2f(v.y); az += bf2f(v.z); aw += bf2f(v.w);
        run += 1.f;
    }
    if (gcur >= 0) {
        atomicAdd(&pooled[gcur * HID + c + 0], ax);
        atomicAdd(&pooled[gcur * HID + c + 1], ay);
        atomicAdd(&pooled[gcur * HID + c + 2], az);
        atomicAdd(&pooled[gcur * HID + c + 3], aw);
        if (lane == 0) atomicAdd(&countsf[gcur], run);
    }
}

// ---------------- head MLP ----------------

__global__ __launch_bounds__(256) void k_mlp(const float* __restrict__ pooled,
                                             const float* __restrict__ countsf,
                                             const float* __restrict__ Wf1,
                                             const float* __restrict__ bf1,
                                             const float* __restrict__ Wf2,
                                             const float* __restrict__ bf2,
                                             float* __restrict__ out) {
    __shared__ float p[HID];
    __shared__ float z[HID];
    int g = blockIdx.x, t = threadIdx.x;
    float cnt = fmaxf(countsf[g], 1.0f);
    p[t] = pooled[g * HID + t] / cnt;
    __syncthreads();
    float accz = bf1[t];
    for (int k = 0; k < HID; ++k)
        accz = fmaf(p[k], Wf1[k * HID + t], accz);
    z[t] = fmaxf(accz, 0.f);
    __syncthreads();
    if (t < NCLS) {
        float o = bf2[t];
        for (int k = 0; k < HID; ++k)
            o = fmaf(z[k], Wf2[k * NCLS + t], o);
        float sp = fmaxf(o, 0.f) + log1pf(expf(-fabsf(o)));
        out[g * NCLS + t] = sp + 0.001f;
    }
}

// ---------------- launch ----------------

extern "C" void kernel_launch(void* const* d_in, const int* in_sizes, int n_in,
                              void* d_out, int out_size, void* d_ws, size_t ws_size,
                              hipStream_t stream) {
    const float* x     = (const float*)d_in[0];
    const int*   ei    = (const int*)d_in[1];
    const int*   batch = (const int*)d_in[2];
    const float* W1    = (const float*)d_in[3];
    const float* b1    = (const float*)d_in[4];
    const float* W2    = (const float*)d_in[5];
    const float* b2    = (const float*)d_in[6];
    const float* Wf1   = (const float*)d_in[7];
    const float* bf1   = (const float*)d_in[8];
    const float* Wf2   = (const float*)d_in[9];
    const float* bf2   = (const float*)d_in[10];
    float* out = (float*)d_out;

    const int* srcv = ei;
    const int* dstv = ei + NE;

    char* p = (char*)d_ws;
    auto take = [&](size_t bytes) -> char* {
        char* q = p; p += (bytes + 255) & ~(size_t)255; return q;
    };
    // big0: xs [NN*128] + xa [NN*128]; reused whole as r [NN*256]
    unsigned short* big0 = (unsigned short*)take((size_t)NN * HID * 2);
    // big1: pairs (12.8MB, dead before GEMM1) then h [NN*256], then out2
    unsigned short* big1 = (unsigned short*)take((size_t)NN * HID * 2);
    unsigned short* xs = big0;
    unsigned short* xa = big0 + (size_t)NN * DIN;
    unsigned short* hB = big1;
    unsigned short* rB = big0;
    unsigned short* o2 = big1;
    int2* pairs = (int2*)big1;                       // alias: dead before hB written
    unsigned short* wt1  = (unsigned short*)take((size_t)DIN * HID * 2);
    unsigned short* wt2  = (unsigned short*)take((size_t)HID * HID * 2);
    int*   histg   = (int*)take((size_t)NBUK * NBLK * 4);
    int*   deg     = (int*)take((size_t)NN * 4);
    int*   offs    = (int*)take((size_t)NN * 4);
    int*   csr     = (int*)take((size_t)NE * 4);
    float* dinv    = (float*)take((size_t)NN * 4);
    float* pooled  = (float*)take((size_t)NG * HID * 4);
    float* countsf = (float*)take((size_t)NG * 4);

    hipMemsetAsync(pooled, 0, (size_t)NG * HID * 4, stream);
    hipMemsetAsync(countsf, 0, (size_t)NG * 4, stream);

    // graph preprocessing: counting-sort CSR build
    k_hist<<<NBLK, 256, 0, stream>>>(dstv, histg);
    k_scan64k<<<1, 1024, 0, stream>>>(histg);
    k_scatter<<<NBLK, 256, 0, stream>>>(srcv, dstv, histg, pairs);
    k_csr<<<NBUK, 256, 0, stream>>>(pairs, histg, csr, deg, dinv, offs);

    // casts
    k_cast_scale_x<<<(NN * DIN / 4 + 255) / 256, 256, 0, stream>>>(x, dinv, xs, NN * DIN / 4);
    k_cast_wt<<<(DIN * HID + 255) / 256, 256, 0, stream>>>(W1, wt1, DIN);
    k_cast_wt<<<(HID * HID + 255) / 256, 256, 0, stream>>>(W2, wt2, HID);

    dim3 gg((NN + 127) / 128, HID / 128);
    // layer 1
    k_agg128<<<(NN + 3) / 4, 256, 0, stream>>>(xs, csr, offs, deg, dinv, xa, NN);
    k_gemm_mfma<1><<<gg, 256, 0, stream>>>(xa, wt1, dinv, b1, hB, NN, DIN);
    // layer 2
    k_agg256<<<(NN + 3) / 4, 256, 0, stream>>>(hB, csr, offs, deg, dinv, rB, NN);
    k_gemm_mfma<2><<<gg, 256, 0, stream>>>(rB, wt2, dinv, b2, o2, NN, HID);

    int pool_waves  = (NN + 15) / 16;
    int pool_blocks = (pool_waves + 3) / 4;
    k_pool<<<pool_blocks, 256, 0, stream>>>(o2, batch, pooled, countsf, NN);
    k_mlp<<<NG, 256, 0, stream>>>(pooled, countsf, Wf1, bf1, Wf2, bf2, out);
}

// Round 5
// 469.565 us; speedup vs baseline: 2.2250x; 1.0006x over previous
//
#include <hip/hip_runtime.h>
#include <math.h>

#define NN   100000
#define NE   1600000
#define DIN  128
#define HID  256
#define NG   64
#define NCLS 10

// counting-sort CSR build parameters
#define NBLK 128          // edge-chunk blocks (NE/NBLK = 12500 exactly)
#define EPB  (NE / NBLK)
#define NBUK 512          // dst buckets
#define NPB  196          // nodes per bucket (512*196 = 100352 >= NN)

using bf16x8 = __attribute__((ext_vector_type(8))) short;
using f32x4  = __attribute__((ext_vector_type(4))) float;

static __device__ __forceinline__ unsigned short f2bf(float f) {
    unsigned u = __float_as_uint(f);
    u += 0x7fff + ((u >> 16) & 1);   // round-to-nearest-even
    return (unsigned short)(u >> 16);
}
static __device__ __forceinline__ float bf2f(unsigned short h) {
    return __uint_as_float(((unsigned)h) << 16);
}

// ---------------- graph preprocessing: bucketed counting sort ----------------

// Pass A: per-(block,bucket) histogram, bucket-major layout histg[bkt*NBLK + blk]
__global__ __launch_bounds__(256) void k_hist(const int* __restrict__ dst,
                                              int* __restrict__ histg) {
    __shared__ int h[NBUK];
    const int t = threadIdx.x;
    for (int i = t; i < NBUK; i += 256) h[i] = 0;
    __syncthreads();
    const int e0 = blockIdx.x * EPB, e1 = e0 + EPB;
    for (int e = e0 + t; e < e1; e += 256)
        atomicAdd(&h[(unsigned)dst[e] / NPB], 1);
    __syncthreads();
    for (int i = t; i < NBUK; i += 256)
        histg[i * NBLK + blockIdx.x] = h[i];
}

// exclusive scan of the 65536-entry histogram, in place (1 block, 1024 thr)
__global__ __launch_bounds__(1024) void k_scan64k(int* __restrict__ d) {
    __shared__ int ts[1024];
    const int t = threadIdx.x;
    const int base = t * 64;
    int s = 0;
    for (int i = 0; i < 64; ++i) s += d[base + i];
    ts[t] = s;
    __syncthreads();
    for (int off = 1; off < 1024; off <<= 1) {
        int u = (t >= off) ? ts[t - off] : 0;
        __syncthreads();
        ts[t] += u;
        __syncthreads();
    }
    int run = ts[t] - s;   // exclusive prefix of this chunk
    for (int i = 0; i < 64; ++i) {
        int v = d[base + i];
        d[base + i] = run;
        run += v;
    }
}

// Pass B: scatter (src,dst) pairs into bucket-sorted order
__global__ __launch_bounds__(256) void k_scatter(const int* __restrict__ src,
                                                 const int* __restrict__ dst,
                                                 const int* __restrict__ offg,
                                                 int2* __restrict__ pairs) {
    __shared__ int cur[NBUK];
    const int t = threadIdx.x;
    for (int i = t; i < NBUK; i += 256) cur[i] = offg[i * NBLK + blockIdx.x];
    __syncthreads();
    const int e0 = blockIdx.x * EPB, e1 = e0 + EPB;
    for (int e = e0 + t; e < e1; e += 256) {
        int d = dst[e];
        int b = (unsigned)d / NPB;
        int p = atomicAdd(&cur[b], 1);
        pairs[p] = make_int2(src[e], d);
    }
}

// Pass C: per-bucket local CSR build + deg + dinv + offs (all L2-local)
__global__ __launch_bounds__(256) void k_csr(const int2* __restrict__ pairs,
                                             const int* __restrict__ offg,
                                             int* __restrict__ csr,
                                             int* __restrict__ deg,
                                             float* __restrict__ dinv,
                                             int* __restrict__ offs) {
    __shared__ int cnt[NPB];
    __shared__ int loff[256];
    __shared__ int cur[NPB];
    const int b = blockIdx.x, t = threadIdx.x;
    const int s     = offg[b * NBLK];
    const int e_end = (b == NBUK - 1) ? NE : offg[(b + 1) * NBLK];
    const int nb0   = b * NPB;
    const int nnod  = min(NPB, NN - nb0);   // <=0 for tail bucket(s)
    if (t < NPB) cnt[t] = 0;
    __syncthreads();
    for (int e = s + t; e < e_end; e += 256)
        atomicAdd(&cnt[pairs[e].y - nb0], 1);
    __syncthreads();
    int v = (t < NPB) ? cnt[t] : 0;
    loff[t] = v;
    __syncthreads();
    for (int off = 1; off < 256; off <<= 1) {
        int u = (t >= off) ? loff[t - off] : 0;
        __syncthreads();
        loff[t] += u;
        __syncthreads();
    }
    int myoff = loff[t] - v;   // exclusive prefix
    __syncthreads();
    loff[t] = myoff;
    if (t < NPB) cur[t] = 0;
    __syncthreads();
    if (t < nnod) {
        int node = nb0 + t;
        int dg = cnt[t];
        deg[node]  = dg;
        dinv[node] = rsqrtf((float)(dg + 1));
        offs[node] = s + myoff;
    }
    for (int e = s + t; e < e_end; e += 256) {
        int2 pr = pairs[e];
        int li = pr.y - nb0;
        int p = atomicAdd(&cur[li], 1);
        csr[s + loff[li] + p] = pr.x;
    }
}

// ---------------- casts ----------------

// xs = bf16(dinv[row] * x[row]) : [NN][128]
__global__ void k_cast_scale_x(const float* __restrict__ x, const float* __restrict__ dinv,
                               unsigned short* __restrict__ xb, int n4) {
    int i = blockIdx.x * blockDim.x + threadIdx.x;
    if (i >= n4) return;
    float dv = dinv[i >> 5];
    const float4 v = *(const float4*)&x[i * 4];
    ushort4 o;
    o.x = f2bf(v.x * dv); o.y = f2bf(v.y * dv);
    o.z = f2bf(v.z * dv); o.w = f2bf(v.w * dv);
    *(ushort4*)&xb[i * 4] = o;
}

// W [K][256] f32 -> Wt [256][K] bf16 (transpose)
__global__ void k_cast_wt(const float* __restrict__ W, unsigned short* __restrict__ Wt, int K) {
    int i = blockIdx.x * blockDim.x + threadIdx.x;
    if (i >= K * HID) return;
    int k = i >> 8;
    int nc = i & 255;
    Wt[nc * K + k] = f2bf(W[i]);
}

// ---------------- MFMA GEMM with fused epilogue ----------------
// MODE 1: out = bf16(dinv[row] * relu(acc + bias[col]))
// MODE 2: out = bf16(relu(acc + bias[col]))

template <int MODE>
__global__ __launch_bounds__(256) void k_gemm_mfma(const unsigned short* __restrict__ A,
                                                   const unsigned short* __restrict__ Wt,
                                                   const float* __restrict__ dinv,
                                                   const float* __restrict__ bias,
                                                   unsigned short* __restrict__ out,
                                                   int M, int K) {
    __shared__ unsigned short As[128 * 40];
    __shared__ unsigned short Bs[128 * 40];
    const int t = threadIdx.x;
    const int lane = t & 63;
    const int wid = t >> 6;
    const int wr = wid >> 1, wc = wid & 1;
    const int bm = blockIdx.x * 128, bn = blockIdx.y * 128;
    const int lr = lane & 15;
    const int ko = (lane >> 4) << 3;

    f32x4 acc[4][4] = {};

    const int r = t >> 2;
    const int kq = (t & 3) << 3;

    for (int kk = 0; kk < K; kk += 32) {
#pragma unroll
        for (int h = 0; h < 128; h += 64) {
            int row = bm + r + h;
            int4 v = make_int4(0, 0, 0, 0);
            if (row < M) v = *(const int4*)&A[(size_t)row * K + kk + kq];
            *(int4*)&As[(r + h) * 40 + kq] = v;
        }
#pragma unroll
        for (int h = 0; h < 128; h += 64) {
            int nrow = bn + r + h;
            int4 v = *(const int4*)&Wt[(size_t)nrow * K + kk + kq];
            *(int4*)&Bs[(r + h) * 40 + kq] = v;
        }
        __syncthreads();
        bf16x8 af[4], bfr[4];
#pragma unroll
        for (int mf = 0; mf < 4; ++mf)
            af[mf] = *(const bf16x8*)&As[(wr * 64 + mf * 16 + lr) * 40 + ko];
#pragma unroll
        for (int nf = 0; nf < 4; ++nf)
            bfr[nf] = *(const bf16x8*)&Bs[(wc * 64 + nf * 16 + lr) * 40 + ko];
#pragma unroll
        for (int mf = 0; mf < 4; ++mf)
#pragma unroll
            for (int nf = 0; nf < 4; ++nf)
                acc[mf][nf] = __builtin_amdgcn_mfma_f32_16x16x32_bf16(af[mf], bfr[nf], acc[mf][nf], 0, 0, 0);
        __syncthreads();
    }

#pragma unroll
    for (int mf = 0; mf < 4; ++mf) {
#pragma unroll
        for (int b = 0; b < 4; ++b) {
            int row = bm + wr * 64 + mf * 16 + (lane >> 4) * 4 + b;
            if (row >= M) continue;
            float dv = (MODE == 1) ? dinv[row] : 1.0f;
#pragma unroll
            for (int nf = 0; nf < 4; ++nf) {
                int col = bn + wc * 64 + nf * 16 + lr;
                float v = fmaxf(acc[mf][nf][b] + bias[col], 0.f);
                if (MODE == 1) v *= dv;
                out[(size_t)row * HID + col] = f2bf(v);
            }
        }
    }
}

// ---------------- aggregation, 256 channels ----------------

__global__ __launch_bounds__(256) void k_agg256(const unsigned short* __restrict__ hs,
                                                const int* __restrict__ csr,
                                                const int* __restrict__ offs,
                                                const int* __restrict__ deg,
                                                const float* __restrict__ dinv,
                                                unsigned short* __restrict__ out, int n) {
    int wid = threadIdx.x >> 6, lane = threadIdx.x & 63;
    int node = blockIdx.x * 4 + wid;
    if (node >= n) return;
    int c = lane << 2;
    const ushort4 self = *(const ushort4*)&hs[(size_t)node * HID + c];
    float a0 = bf2f(self.x), a1 = bf2f(self.y), a2 = bf2f(self.z), a3 = bf2f(self.w);
    int s0 = offs[node], cnt = deg[node];
    for (int base = 0; base < cnt; base += 64) {
        int nb = min(64, cnt - base);
        int idx = (lane < nb) ? csr[s0 + base + lane] : 0;
        int i = 0;
        for (; i + 4 <= nb; i += 4) {
            int j0 = __shfl(idx, i + 0);
            int j1 = __shfl(idx, i + 1);
            int j2 = __shfl(idx, i + 2);
            int j3 = __shfl(idx, i + 3);
            const ushort4 v0 = *(const ushort4*)&hs[(size_t)j0 * HID + c];
            const ushort4 v1 = *(const ushort4*)&hs[(size_t)j1 * HID + c];
            const ushort4 v2 = *(const ushort4*)&hs[(size_t)j2 * HID + c];
            const ushort4 v3 = *(const ushort4*)&hs[(size_t)j3 * HID + c];
            a0 += bf2f(v0.x) + bf2f(v1.x) + bf2f(v2.x) + bf2f(v3.x);
            a1 += bf2f(v0.y) + bf2f(v1.y) + bf2f(v2.y) + bf2f(v3.y);
            a2 += bf2f(v0.z) + bf2f(v1.z) + bf2f(v2.z) + bf2f(v3.z);
            a3 += bf2f(v0.w) + bf2f(v1.w) + bf2f(v2.w) + bf2f(v3.w);
        }
        for (; i < nb; ++i) {
            int j = __shfl(idx, i);
            const ushort4 v = *(const ushort4*)&hs[(size_t)j * HID + c];
            a0 += bf2f(v.x); a1 += bf2f(v.y); a2 += bf2f(v.z); a3 += bf2f(v.w);
        }
    }
    float dv = dinv[node];
    ushort4 r;
    r.x = f2bf(dv * a0); r.y = f2bf(dv * a1);
    r.z = f2bf(dv * a2); r.w = f2bf(dv * a3);
    *(ushort4*)&out[(size_t)node * HID + c] = r;
}

// ---------------- aggregation, 128 channels (pre-GEMM1) ----------------

__global__ __launch_bounds__(256) void k_agg128(const unsigned short* __restrict__ xs,
                                                const int* __restrict__ csr,
                                                const int* __restrict__ offs,
                                                const int* __restrict__ deg,
                                                const float* __restrict__ dinv,
                                                unsigned short* __restrict__ out, int n) {
    int wid = threadIdx.x >> 6, lane = threadIdx.x & 63;
    int node = blockIdx.x * 4 + wid;
    if (node >= n) return;
    int half = lane >> 5, l32 = lane & 31;
    int c = l32 << 2;
    float a0 = 0.f, a1 = 0.f, a2 = 0.f, a3 = 0.f;
    if (half == 0) {
        const ushort4 s = *(const ushort4*)&xs[(size_t)node * DIN + c];
        a0 = bf2f(s.x); a1 = bf2f(s.y); a2 = bf2f(s.z); a3 = bf2f(s.w);
    }
    int s0 = offs[node], cnt = deg[node];
    for (int base = 0; base < cnt; base += 64) {
        int nb = min(64, cnt - base);
        int idx = (lane < nb) ? csr[s0 + base + lane] : 0;
        for (int i = 0; i < nb; i += 4) {
            int e0 = i + half;
            int e1 = i + 2 + half;
            int j0 = __shfl(idx, e0 < nb ? e0 : 0);
            int j1 = __shfl(idx, e1 < nb ? e1 : 0);
            if (e0 < nb) {
                const ushort4 v = *(const ushort4*)&xs[(size_t)j0 * DIN + c];
                a0 += bf2f(v.x); a1 += bf2f(v.y); a2 += bf2f(v.z); a3 += bf2f(v.w);
            }
            if (e1 < nb) {
                const ushort4 v = *(const ushort4*)&xs[(size_t)j1 * DIN + c];
                a0 += bf2f(v.x); a1 += bf2f(v.y); a2 += bf2f(v.z); a3 += bf2f(v.w);
            }
        }
    }
    a0 += __shfl_xor(a0, 32);
    a1 += __shfl_xor(a1, 32);
    a2 += __shfl_xor(a2, 32);
    a3 += __shfl_xor(a3, 32);
    if (half == 0) {
        float dv = dinv[node];
        ushort4 r;
        r.x = f2bf(dv * a0); r.y = f2bf(dv * a1);
        r.z = f2bf(dv * a2); r.w = f2bf(dv * a3);
        *(ushort4*)&out[(size_t)node * DIN + c] = r;
    }
}

// ---------------- pooling ----------------

__global__ __launch_bounds__(256) void k_pool(const unsigned short* __restrict__ a,
                                              const int* __restrict__ batch,
                                              float* __restrict__ pooled,
                                              float* __restrict__ countsf, int n) {
    int wid = threadIdx.x >> 6, lane = threadIdx.x & 63;
    int wg = blockIdx.x * 4 + wid;
    int n0 = wg * 16;
    if (n0 >= n) return;
    int n1 = min(n0 + 16, n);
    int c = lane << 2;
    float ax = 0.f, ay = 0.f, az = 0.f, aw = 0.f;
    int gcur = -1; float run = 0.f;
    for (int nd = n0; nd < n1; ++nd) {
        int g = batch[nd];
        if (g != gcur) {
            if (gcur >= 0) {
                atomicAdd(&pooled[gcur * HID + c + 0], ax);
                atomicAdd(&pooled[gcur * HID + c + 1], ay);
                atomicAdd(&pooled[gcur * HID + c + 2], az);
                atomicAdd(&pooled[gcur * HID + c + 3], aw);
                if (lane == 0) atomicAdd(&countsf[gcur], run);
            }
            gcur = g; ax = ay = az = aw = 0.f; run = 0.f;
        }
        const ushort4 v = *(const ushort4*)&a[(size_t)nd * HID + c];
        ax += bf2f(v.x); ay += bf2f(v.y); az += bf2f(v.z); aw += bf2f(v.w);
        run += 1.f;
    }
    if (gcur >= 0) {
        atomicAdd(&pooled[gcur * HID + c + 0], ax);
        atomicAdd(&pooled[gcur * HID + c + 1], ay);
        atomicAdd(&pooled[gcur * HID + c + 2], az);
        atomicAdd(&pooled[gcur * HID + c + 3], aw);
        if (lane == 0) atomicAdd(&countsf[gcur], run);
    }
}

// ---------------- head MLP ----------------

__global__ __launch_bounds__(256) void k_mlp(const float* __restrict__ pooled,
                                             const float* __restrict__ countsf,
                                             const float* __restrict__ Wf1,
                                             const float* __restrict__ bf1,
                                             const float* __restrict__ Wf2,
                                             const float* __restrict__ bf2,
                                             float* __restrict__ out) {
    __shared__ float p[HID];
    __shared__ float z[HID];
    int g = blockIdx.x, t = threadIdx.x;
    float cnt = fmaxf(countsf[g], 1.0f);
    p[t] = pooled[g * HID + t] / cnt;
    __syncthreads();
    float accz = bf1[t];
    for (int k = 0; k < HID; ++k)
        accz = fmaf(p[k], Wf1[k * HID + t], accz);
    z[t] = fmaxf(accz, 0.f);
    __syncthreads();
    if (t < NCLS) {
        float o = bf2[t];
        for (int k = 0; k < HID; ++k)
            o = fmaf(z[k], Wf2[k * NCLS + t], o);
        float sp = fmaxf(o, 0.f) + log1pf(expf(-fabsf(o)));
        out[g * NCLS + t] = sp + 0.001f;
    }
}

// ---------------- launch ----------------

extern "C" void kernel_launch(void* const* d_in, const int* in_sizes, int n_in,
                              void* d_out, int out_size, void* d_ws, size_t ws_size,
                              hipStream_t stream) {
    const float* x     = (const float*)d_in[0];
    const int*   ei    = (const int*)d_in[1];
    const int*   batch = (const int*)d_in[2];
    const float* W1    = (const float*)d_in[3];
    const float* b1    = (const float*)d_in[4];
    const float* W2    = (const float*)d_in[5];
    const float* b2    = (const float*)d_in[6];
    const float* Wf1   = (const float*)d_in[7];
    const float* bf1   = (const float*)d_in[8];
    const float* Wf2   = (const float*)d_in[9];
    const float* bf2   = (const float*)d_in[10];
    float* out = (float*)d_out;

    const int* srcv = ei;
    const int* dstv = ei + NE;

    char* p = (char*)d_ws;
    auto take = [&](size_t bytes) -> char* {
        char* q = p; p += (bytes + 255) & ~(size_t)255; return q;
    };
    // big0: xs [NN*128] + xa [NN*128]; reused whole as r [NN*256]
    unsigned short* big0 = (unsigned short*)take((size_t)NN * HID * 2);
    // big1: pairs (12.8MB, dead before GEMM1) then h [NN*256], then out2
    unsigned short* big1 = (unsigned short*)take((size_t)NN * HID * 2);
    unsigned short* xs = big0;
    unsigned short* xa = big0 + (size_t)NN * DIN;
    unsigned short* hB = big1;
    unsigned short* rB = big0;
    unsigned short* o2 = big1;
    int2* pairs = (int2*)big1;                       // alias: dead before hB written
    unsigned short* wt1  = (unsigned short*)take((size_t)DIN * HID * 2);
    unsigned short* wt2  = (unsigned short*)take((size_t)HID * HID * 2);
    int*   histg   = (int*)take((size_t)NBUK * NBLK * 4);
    int*   deg     = (int*)take((size_t)NN * 4);
    int*   offs    = (int*)take((size_t)NN * 4);
    int*   csr     = (int*)take((size_t)NE * 4);
    float* dinv    = (float*)take((size_t)NN * 4);
    float* pooled  = (float*)take((size_t)NG * HID * 4);
    float* countsf = (float*)take((size_t)NG * 4);

    hipMemsetAsync(pooled, 0, (size_t)NG * HID * 4, stream);
    hipMemsetAsync(countsf, 0, (size_t)NG * 4, stream);

    // graph preprocessing: counting-sort CSR build
    k_hist<<<NBLK, 256, 0, stream>>>(dstv, histg);
    k_scan64k<<<1, 1024, 0, stream>>>(histg);
    k_scatter<<<NBLK, 256, 0, stream>>>(srcv, dstv, histg, pairs);
    k_csr<<<NBUK, 256, 0, stream>>>(pairs, histg, csr, deg, dinv, offs);

    // casts
    k_cast_scale_x<<<(NN * DIN / 4 + 255) / 256, 256, 0, stream>>>(x, dinv, xs, NN * DIN / 4);
    k_cast_wt<<<(DIN * HID + 255) / 256, 256, 0, stream>>>(W1, wt1, DIN);
    k_cast_wt<<<(HID * HID + 255) / 256, 256, 0, stream>>>(W2, wt2, HID);

    dim3 gg((NN + 127) / 128, HID / 128);
    // layer 1
    k_agg128<<<(NN + 3) / 4, 256, 0, stream>>>(xs, csr, offs, deg, dinv, xa, NN);
    k_gemm_mfma<1><<<gg, 256, 0, stream>>>(xa, wt1, dinv, b1, hB, NN, DIN);
    // layer 2
    k_agg256<<<(NN + 3) / 4, 256, 0, stream>>>(hB, csr, offs, deg, dinv, rB, NN);
    k_gemm_mfma<2><<<gg, 256, 0, stream>>>(rB, wt2, dinv, b2, o2, NN, HID);

    int pool_waves  = (NN + 15) / 16;
    int pool_blocks = (pool_waves + 3) / 4;
    k_pool<<<pool_blocks, 256, 0, stream>>>(o2, batch, pooled, countsf, NN);
    k_mlp<<<NG, 256, 0, stream>>>(pooled, countsf, Wf1, bf1, Wf2, bf2, out);
}

// Round 6
// 468.900 us; speedup vs baseline: 2.2282x; 1.0014x over previous
//
#include <hip/hip_runtime.h>
#include <math.h>

#define NN   100000
#define NE   1600000
#define DIN  128
#define HID  256
#define NG   64
#define NCLS 10

// counting-sort CSR build parameters
#define NBLK 128          // edge-chunk blocks (NE/NBLK = 12500 exactly)
#define EPB  (NE / NBLK)
#define NBUK 512          // dst buckets
#define NPB  196          // nodes per bucket (512*196 = 100352 >= NN)

using bf16x8 = __attribute__((ext_vector_type(8))) short;
using f32x4  = __attribute__((ext_vector_type(4))) float;

static __device__ __forceinline__ unsigned short f2bf(float f) {
    unsigned u = __float_as_uint(f);
    u += 0x7fff + ((u >> 16) & 1);   // round-to-nearest-even
    return (unsigned short)(u >> 16);
}
static __device__ __forceinline__ float bf2f(unsigned short h) {
    return __uint_as_float(((unsigned)h) << 16);
}

// ---------------- graph preprocessing: bucketed counting sort ----------------

// Pass A: per-(block,bucket) histogram, bucket-major layout histg[bkt*NBLK + blk]
__global__ __launch_bounds__(256) void k_hist(const int* __restrict__ dst,
                                              int* __restrict__ histg) {
    __shared__ int h[NBUK];
    const int t = threadIdx.x;
    for (int i = t; i < NBUK; i += 256) h[i] = 0;
    __syncthreads();
    const int e0 = blockIdx.x * EPB, e1 = e0 + EPB;
    for (int e = e0 + t; e < e1; e += 256)
        atomicAdd(&h[(unsigned)dst[e] / NPB], 1);
    __syncthreads();
    for (int i = t; i < NBUK; i += 256)
        histg[i * NBLK + blockIdx.x] = h[i];
}

// exclusive scan of the 65536-entry histogram, in place (1 block, 1024 thr)
__global__ __launch_bounds__(1024) void k_scan64k(int* __restrict__ d) {
    __shared__ int ts[1024];
    const int t = threadIdx.x;
    const int base = t * 64;
    int s = 0;
    for (int i = 0; i < 64; ++i) s += d[base + i];
    ts[t] = s;
    __syncthreads();
    for (int off = 1; off < 1024; off <<= 1) {
        int u = (t >= off) ? ts[t - off] : 0;
        __syncthreads();
        ts[t] += u;
        __syncthreads();
    }
    int run = ts[t] - s;   // exclusive prefix of this chunk
    for (int i = 0; i < 64; ++i) {
        int v = d[base + i];
        d[base + i] = run;
        run += v;
    }
}

// Pass B: scatter (src,dst) pairs into bucket-sorted order
__global__ __launch_bounds__(256) void k_scatter(const int* __restrict__ src,
                                                 const int* __restrict__ dst,
                                                 const int* __restrict__ offg,
                                                 int2* __restrict__ pairs) {
    __shared__ int cur[NBUK];
    const int t = threadIdx.x;
    for (int i = t; i < NBUK; i += 256) cur[i] = offg[i * NBLK + blockIdx.x];
    __syncthreads();
    const int e0 = blockIdx.x * EPB, e1 = e0 + EPB;
    for (int e = e0 + t; e < e1; e += 256) {
        int d = dst[e];
        int b = (unsigned)d / NPB;
        int p = atomicAdd(&cur[b], 1);
        pairs[p] = make_int2(src[e], d);
    }
}

// Pass C: per-bucket local CSR build + deg + dinv + offs (all L2-local)
__global__ __launch_bounds__(256) void k_csr(const int2* __restrict__ pairs,
                                             const int* __restrict__ offg,
                                             int* __restrict__ csr,
                                             int* __restrict__ deg,
                                             float* __restrict__ dinv,
                                             int* __restrict__ offs) {
    __shared__ int cnt[NPB];
    __shared__ int loff[256];
    __shared__ int cur[NPB];
    const int b = blockIdx.x, t = threadIdx.x;
    const int s     = offg[b * NBLK];
    const int e_end = (b == NBUK - 1) ? NE : offg[(b + 1) * NBLK];
    const int nb0   = b * NPB;
    const int nnod  = min(NPB, NN - nb0);   // <=0 for tail bucket(s)
    if (t < NPB) cnt[t] = 0;
    __syncthreads();
    for (int e = s + t; e < e_end; e += 256)
        atomicAdd(&cnt[pairs[e].y - nb0], 1);
    __syncthreads();
    int v = (t < NPB) ? cnt[t] : 0;
    loff[t] = v;
    __syncthreads();
    for (int off = 1; off < 256; off <<= 1) {
        int u = (t >= off) ? loff[t - off] : 0;
        __syncthreads();
        loff[t] += u;
        __syncthreads();
    }
    int myoff = loff[t] - v;   // exclusive prefix
    __syncthreads();
    loff[t] = myoff;
    if (t < NPB) cur[t] = 0;
    __syncthreads();
    if (t < nnod) {
        int node = nb0 + t;
        int dg = cnt[t];
        deg[node]  = dg;
        dinv[node] = rsqrtf((float)(dg + 1));
        offs[node] = s + myoff;
    }
    for (int e = s + t; e < e_end; e += 256) {
        int2 pr = pairs[e];
        int li = pr.y - nb0;
        int p = atomicAdd(&cur[li], 1);
        csr[s + loff[li] + p] = pr.x;
    }
}

// ---------------- casts ----------------

// xs = bf16(dinv[row] * x[row]) : [NN][128]
__global__ void k_cast_scale_x(const float* __restrict__ x, const float* __restrict__ dinv,
                               unsigned short* __restrict__ xb, int n4) {
    int i = blockIdx.x * blockDim.x + threadIdx.x;
    if (i >= n4) return;
    float dv = dinv[i >> 5];
    const float4 v = *(const float4*)&x[i * 4];
    ushort4 o;
    o.x = f2bf(v.x * dv); o.y = f2bf(v.y * dv);
    o.z = f2bf(v.z * dv); o.w = f2bf(v.w * dv);
    *(ushort4*)&xb[i * 4] = o;
}

// W [K][256] f32 -> Wt [256][K] bf16 (transpose)
__global__ void k_cast_wt(const float* __restrict__ W, unsigned short* __restrict__ Wt, int K) {
    int i = blockIdx.x * blockDim.x + threadIdx.x;
    if (i >= K * HID) return;
    int k = i >> 8;
    int nc = i & 255;
    Wt[nc * K + k] = f2bf(W[i]);
}

// ---------------- MFMA GEMM with fused epilogue ----------------
// MODE 1: out = bf16(dinv[row] * relu(acc + bias[col]))
// MODE 2: out = bf16(relu(acc + bias[col]))

template <int MODE>
__global__ __launch_bounds__(256) void k_gemm_mfma(const unsigned short* __restrict__ A,
                                                   const unsigned short* __restrict__ Wt,
                                                   const float* __restrict__ dinv,
                                                   const float* __restrict__ bias,
                                                   unsigned short* __restrict__ out,
                                                   int M, int K) {
    __shared__ unsigned short As[128 * 40];
    __shared__ unsigned short Bs[128 * 40];
    const int t = threadIdx.x;
    const int lane = t & 63;
    const int wid = t >> 6;
    const int wr = wid >> 1, wc = wid & 1;
    const int bm = blockIdx.x * 128, bn = blockIdx.y * 128;
    const int lr = lane & 15;
    const int ko = (lane >> 4) << 3;

    f32x4 acc[4][4] = {};

    const int r = t >> 2;
    const int kq = (t & 3) << 3;

    for (int kk = 0; kk < K; kk += 32) {
#pragma unroll
        for (int h = 0; h < 128; h += 64) {
            int row = bm + r + h;
            int4 v = make_int4(0, 0, 0, 0);
            if (row < M) v = *(const int4*)&A[(size_t)row * K + kk + kq];
            *(int4*)&As[(r + h) * 40 + kq] = v;
        }
#pragma unroll
        for (int h = 0; h < 128; h += 64) {
            int nrow = bn + r + h;
            int4 v = *(const int4*)&Wt[(size_t)nrow * K + kk + kq];
            *(int4*)&Bs[(r + h) * 40 + kq] = v;
        }
        __syncthreads();
        bf16x8 af[4], bfr[4];
#pragma unroll
        for (int mf = 0; mf < 4; ++mf)
            af[mf] = *(const bf16x8*)&As[(wr * 64 + mf * 16 + lr) * 40 + ko];
#pragma unroll
        for (int nf = 0; nf < 4; ++nf)
            bfr[nf] = *(const bf16x8*)&Bs[(wc * 64 + nf * 16 + lr) * 40 + ko];
#pragma unroll
        for (int mf = 0; mf < 4; ++mf)
#pragma unroll
            for (int nf = 0; nf < 4; ++nf)
                acc[mf][nf] = __builtin_amdgcn_mfma_f32_16x16x32_bf16(af[mf], bfr[nf], acc[mf][nf], 0, 0, 0);
        __syncthreads();
    }

#pragma unroll
    for (int mf = 0; mf < 4; ++mf) {
#pragma unroll
        for (int b = 0; b < 4; ++b) {
            int row = bm + wr * 64 + mf * 16 + (lane >> 4) * 4 + b;
            if (row >= M) continue;
            float dv = (MODE == 1) ? dinv[row] : 1.0f;
#pragma unroll
            for (int nf = 0; nf < 4; ++nf) {
                int col = bn + wc * 64 + nf * 16 + lr;
                float v = fmaxf(acc[mf][nf][b] + bias[col], 0.f);
                if (MODE == 1) v *= dv;
                out[(size_t)row * HID + col] = f2bf(v);
            }
        }
    }
}

// ---------------- aggregation, 256 channels ----------------

__global__ __launch_bounds__(256) void k_agg256(const unsigned short* __restrict__ hs,
                                                const int* __restrict__ csr,
                                                const int* __restrict__ offs,
                                                const int* __restrict__ deg,
                                                const float* __restrict__ dinv,
                                                unsigned short* __restrict__ out, int n) {
    int wid = threadIdx.x >> 6, lane = threadIdx.x & 63;
    int node = blockIdx.x * 4 + wid;
    if (node >= n) return;
    int c = lane << 2;
    const ushort4 self = *(const ushort4*)&hs[(size_t)node * HID + c];
    float a0 = bf2f(self.x), a1 = bf2f(self.y), a2 = bf2f(self.z), a3 = bf2f(self.w);
    int s0 = offs[node], cnt = deg[node];
    for (int base = 0; base < cnt; base += 64) {
        int nb = min(64, cnt - base);
        int idx = (lane < nb) ? csr[s0 + base + lane] : 0;
        int i = 0;
        for (; i + 4 <= nb; i += 4) {
            int j0 = __shfl(idx, i + 0);
            int j1 = __shfl(idx, i + 1);
            int j2 = __shfl(idx, i + 2);
            int j3 = __shfl(idx, i + 3);
            const ushort4 v0 = *(const ushort4*)&hs[(size_t)j0 * HID + c];
            const ushort4 v1 = *(const ushort4*)&hs[(size_t)j1 * HID + c];
            const ushort4 v2 = *(const ushort4*)&hs[(size_t)j2 * HID + c];
            const ushort4 v3 = *(const ushort4*)&hs[(size_t)j3 * HID + c];
            a0 += bf2f(v0.x) + bf2f(v1.x) + bf2f(v2.x) + bf2f(v3.x);
            a1 += bf2f(v0.y) + bf2f(v1.y) + bf2f(v2.y) + bf2f(v3.y);
            a2 += bf2f(v0.z) + bf2f(v1.z) + bf2f(v2.z) + bf2f(v3.z);
            a3 += bf2f(v0.w) + bf2f(v1.w) + bf2f(v2.w) + bf2f(v3.w);
        }
        for (; i < nb; ++i) {
            int j = __shfl(idx, i);
            const ushort4 v = *(const ushort4*)&hs[(size_t)j * HID + c];
            a0 += bf2f(v.x); a1 += bf2f(v.y); a2 += bf2f(v.z); a3 += bf2f(v.w);
        }
    }
    float dv = dinv[node];
    ushort4 r;
    r.x = f2bf(dv * a0); r.y = f2bf(dv * a1);
    r.z = f2bf(dv * a2); r.w = f2bf(dv * a3);
    *(ushort4*)&out[(size_t)node * HID + c] = r;
}

// ---------------- aggregation, 128 channels (pre-GEMM1) ----------------

__global__ __launch_bounds__(256) void k_agg128(const unsigned short* __restrict__ xs,
                                                const int* __restrict__ csr,
                                                const int* __restrict__ offs,
                                                const int* __restrict__ deg,
                                                const float* __restrict__ dinv,
                                                unsigned short* __restrict__ out, int n) {
    int wid = threadIdx.x >> 6, lane = threadIdx.x & 63;
    int node = blockIdx.x * 4 + wid;
    if (node >= n) return;
    int half = lane >> 5, l32 = lane & 31;
    int c = l32 << 2;
    float a0 = 0.f, a1 = 0.f, a2 = 0.f, a3 = 0.f;
    if (half == 0) {
        const ushort4 s = *(const ushort4*)&xs[(size_t)node * DIN + c];
        a0 = bf2f(s.x); a1 = bf2f(s.y); a2 = bf2f(s.z); a3 = bf2f(s.w);
    }
    int s0 = offs[node], cnt = deg[node];
    for (int base = 0; base < cnt; base += 64) {
        int nb = min(64, cnt - base);
        int idx = (lane < nb) ? csr[s0 + base + lane] : 0;
        for (int i = 0; i < nb; i += 4) {
            int e0 = i + half;
            int e1 = i + 2 + half;
            int j0 = __shfl(idx, e0 < nb ? e0 : 0);
            int j1 = __shfl(idx, e1 < nb ? e1 : 0);
            if (e0 < nb) {
                const ushort4 v = *(const ushort4*)&xs[(size_t)j0 * DIN + c];
                a0 += bf2f(v.x); a1 += bf2f(v.y); a2 += bf2f(v.z); a3 += bf2f(v.w);
            }
            if (e1 < nb) {
                const ushort4 v = *(const ushort4*)&xs[(size_t)j1 * DIN + c];
                a0 += bf2f(v.x); a1 += bf2f(v.y); a2 += bf2f(v.z); a3 += bf2f(v.w);
            }
        }
    }
    a0 += __shfl_xor(a0, 32);
    a1 += __shfl_xor(a1, 32);
    a2 += __shfl_xor(a2, 32);
    a3 += __shfl_xor(a3, 32);
    if (half == 0) {
        float dv = dinv[node];
        ushort4 r;
        r.x = f2bf(dv * a0); r.y = f2bf(dv * a1);
        r.z = f2bf(dv * a2); r.w = f2bf(dv * a3);
        *(ushort4*)&out[(size_t)node * DIN + c] = r;
    }
}

// ---------------- pooling ----------------

__global__ __launch_bounds__(256) void k_pool(const unsigned short* __restrict__ a,
                                              const int* __restrict__ batch,
                                              float* __restrict__ pooled,
                                              float* __restrict__ countsf, int n) {
    int wid = threadIdx.x >> 6, lane = threadIdx.x & 63;
    int wg = blockIdx.x * 4 + wid;
    int n0 = wg * 16;
    if (n0 >= n) return;
    int n1 = min(n0 + 16, n);
    int c = lane << 2;
    float ax = 0.f, ay = 0.f, az = 0.f, aw = 0.f;
    int gcur = -1; float run = 0.f;
    for (int nd = n0; nd < n1; ++nd) {
        int g = batch[nd];
        if (g != gcur) {
            if (gcur >= 0) {
                atomicAdd(&pooled[gcur * HID + c + 0], ax);
                atomicAdd(&pooled[gcur * HID + c + 1], ay);
                atomicAdd(&pooled[gcur * HID + c + 2], az);
                atomicAdd(&pooled[gcur * HID + c + 3], aw);
                if (lane == 0) atomicAdd(&countsf[gcur], run);
            }
            gcur = g; ax = ay = az = aw = 0.f; run = 0.f;
        }
        const ushort4 v = *(const ushort4*)&a[(size_t)nd * HID + c];
        ax += bf2f(v.x); ay += bf2f(v.y); az += bf2f(v.z); aw += bf2f(v.w);
        run += 1.f;
    }
    if (gcur >= 0) {
        atomicAdd(&pooled[gcur * HID + c + 0], ax);
        atomicAdd(&pooled[gcur * HID + c + 1], ay);
        atomicAdd(&pooled[gcur * HID + c + 2], az);
        atomicAdd(&pooled[gcur * HID + c + 3], aw);
        if (lane == 0) atomicAdd(&countsf[gcur], run);
    }
}

// ---------------- head MLP ----------------

__global__ __launch_bounds__(256) void k_mlp(const float* __restrict__ pooled,
                                             const float* __restrict__ countsf,
                                             const float* __restrict__ Wf1,
                                             const float* __restrict__ bf1,
                                             const float* __restrict__ Wf2,
                                             const float* __restrict__ bf2,
                                             float* __restrict__ out) {
    __shared__ float p[HID];
    __shared__ float z[HID];
    int g = blockIdx.x, t = threadIdx.x;
    float cnt = fmaxf(countsf[g], 1.0f);
    p[t] = pooled[g * HID + t] / cnt;
    __syncthreads();
    float accz = bf1[t];
    for (int k = 0; k < HID; ++k)
        accz = fmaf(p[k], Wf1[k * HID + t], accz);
    z[t] = fmaxf(accz, 0.f);
    __syncthreads();
    if (t < NCLS) {
        float o = bf2[t];
        for (int k = 0; k < HID; ++k)
            o = fmaf(z[k], Wf2[k * NCLS + t], o);
        float sp = fmaxf(o, 0.f) + log1pf(expf(-fabsf(o)));
        out[g * NCLS + t] = sp + 0.001f;
    }
}

// ---------------- launch ----------------

extern "C" void kernel_launch(void* const* d_in, const int* in_sizes, int n_in,
                              void* d_out, int out_size, void* d_ws, size_t ws_size,
                              hipStream_t stream) {
    const float* x     = (const float*)d_in[0];
    const int*   ei    = (const int*)d_in[1];
    const int*   batch = (const int*)d_in[2];
    const float* W1    = (const float*)d_in[3];
    const float* b1    = (const float*)d_in[4];
    const float* W2    = (const float*)d_in[5];
    const float* b2    = (const float*)d_in[6];
    const float* Wf1   = (const float*)d_in[7];
    const float* bf1   = (const float*)d_in[8];
    const float* Wf2   = (const float*)d_in[9];
    const float* bf2   = (const float*)d_in[10];
    float* out = (float*)d_out;

    const int* srcv = ei;
    const int* dstv = ei + NE;

    char* p = (char*)d_ws;
    auto take = [&](size_t bytes) -> char* {
        char* q = p; p += (bytes + 255) & ~(size_t)255; return q;
    };
    // big0: xs [NN*128] + xa [NN*128]; reused whole as r [NN*256]
    unsigned short* big0 = (unsigned short*)take((size_t)NN * HID * 2);
    // big1: pairs (12.8MB, dead before GEMM1) then h [NN*256], then out2
    unsigned short* big1 = (unsigned short*)take((size_t)NN * HID * 2);
    unsigned short* xs = big0;
    unsigned short* xa = big0 + (size_t)NN * DIN;
    unsigned short* hB = big1;
    unsigned short* rB = big0;
    unsigned short* o2 = big1;
    int2* pairs = (int2*)big1;                       // alias: dead before hB written
    unsigned short* wt1  = (unsigned short*)take((size_t)DIN * HID * 2);
    unsigned short* wt2  = (unsigned short*)take((size_t)HID * HID * 2);
    int*   histg   = (int*)take((size_t)NBUK * NBLK * 4);
    int*   deg     = (int*)take((size_t)NN * 4);
    int*   offs    = (int*)take((size_t)NN * 4);
    int*   csr     = (int*)take((size_t)NE * 4);
    float* dinv    = (float*)take((size_t)NN * 4);
    float* pooled  = (float*)take((size_t)NG * HID * 4);
    float* countsf = (float*)take((size_t)NG * 4);

    hipMemsetAsync(pooled, 0, (size_t)NG * HID * 4, stream);
    hipMemsetAsync(countsf, 0, (size_t)NG * 4, stream);

    // graph preprocessing: counting-sort CSR build
    k_hist<<<NBLK, 256, 0, stream>>>(dstv, histg);
    k_scan64k<<<1, 1024, 0, stream>>>(histg);
    k_scatter<<<NBLK, 256, 0, stream>>>(srcv, dstv, histg, pairs);
    k_csr<<<NBUK, 256, 0, stream>>>(pairs, histg, csr, deg, dinv, offs);

    // casts
    k_cast_scale_x<<<(NN * DIN / 4 + 255) / 256, 256, 0, stream>>>(x, dinv, xs, NN * DIN / 4);
    k_cast_wt<<<(DIN * HID + 255) / 256, 256, 0, stream>>>(W1, wt1, DIN);
    k_cast_wt<<<(HID * HID + 255) / 256, 256, 0, stream>>>(W2, wt2, HID);

    dim3 gg((NN + 127) / 128, HID / 128);
    // layer 1
    k_agg128<<<(NN + 3) / 4, 256, 0, stream>>>(xs, csr, offs, deg, dinv, xa, NN);
    k_gemm_mfma<1><<<gg, 256, 0, stream>>>(xa, wt1, dinv, b1, hB, NN, DIN);
    // layer 2
    k_agg256<<<(NN + 3) / 4, 256, 0, stream>>>(hB, csr, offs, deg, dinv, rB, NN);
    k_gemm_mfma<2><<<gg, 256, 0, stream>>>(rB, wt2, dinv, b2, o2, NN, HID);

    int pool_waves  = (NN + 15) / 16;
    int pool_blocks = (pool_waves + 3) / 4;
    k_pool<<<pool_blocks, 256, 0, stream>>>(o2, batch, pooled, countsf, NN);
    k_mlp<<<NG, 256, 0, stream>>>(pooled, countsf, Wf1, bf1, Wf2, bf2, out);
}

// Round 7
// 453.793 us; speedup vs baseline: 2.3023x; 1.0333x over previous
//
#include <hip/hip_runtime.h>
#include <math.h>

#define NN   100000
#define NE   1600000
#define DIN  128
#define HID  256
#define NG   64
#define NCLS 10

// counting-sort CSR build parameters
#define NBLK 128          // edge-chunk blocks (NE/NBLK = 12500 exactly)
#define EPB  (NE / NBLK)
#define NBUK 512          // dst buckets
#define NPB  196          // nodes per bucket (512*196 = 100352 >= NN)

using bf16x8 = __attribute__((ext_vector_type(8))) short;
using f32x4  = __attribute__((ext_vector_type(4))) float;

static __device__ __forceinline__ unsigned short f2bf(float f) {
    unsigned u = __float_as_uint(f);
    u += 0x7fff + ((u >> 16) & 1);   // round-to-nearest-even
    return (unsigned short)(u >> 16);
}
static __device__ __forceinline__ float bf2f(unsigned short h) {
    return __uint_as_float(((unsigned)h) << 16);
}

// ---------------- graph preprocessing: bucketed counting sort ----------------

__global__ __launch_bounds__(256) void k_hist(const int* __restrict__ dst,
                                              int* __restrict__ histg) {
    __shared__ int h[NBUK];
    const int t = threadIdx.x;
    for (int i = t; i < NBUK; i += 256) h[i] = 0;
    __syncthreads();
    const int e0 = blockIdx.x * EPB, e1 = e0 + EPB;
    for (int e = e0 + t; e < e1; e += 256)
        atomicAdd(&h[(unsigned)dst[e] / NPB], 1);
    __syncthreads();
    for (int i = t; i < NBUK; i += 256)
        histg[i * NBLK + blockIdx.x] = h[i];
}

__global__ __launch_bounds__(1024) void k_scan64k(int* __restrict__ d) {
    __shared__ int ts[1024];
    const int t = threadIdx.x;
    const int base = t * 64;
    int s = 0;
    for (int i = 0; i < 64; ++i) s += d[base + i];
    ts[t] = s;
    __syncthreads();
    for (int off = 1; off < 1024; off <<= 1) {
        int u = (t >= off) ? ts[t - off] : 0;
        __syncthreads();
        ts[t] += u;
        __syncthreads();
    }
    int run = ts[t] - s;
    for (int i = 0; i < 64; ++i) {
        int v = d[base + i];
        d[base + i] = run;
        run += v;
    }
}

__global__ __launch_bounds__(256) void k_scatter(const int* __restrict__ src,
                                                 const int* __restrict__ dst,
                                                 const int* __restrict__ offg,
                                                 int2* __restrict__ pairs) {
    __shared__ int cur[NBUK];
    const int t = threadIdx.x;
    for (int i = t; i < NBUK; i += 256) cur[i] = offg[i * NBLK + blockIdx.x];
    __syncthreads();
    const int e0 = blockIdx.x * EPB, e1 = e0 + EPB;
    for (int e = e0 + t; e < e1; e += 256) {
        int d = dst[e];
        int b = (unsigned)d / NPB;
        int p = atomicAdd(&cur[b], 1);
        pairs[p] = make_int2(src[e], d);
    }
}

__global__ __launch_bounds__(256) void k_csr(const int2* __restrict__ pairs,
                                             const int* __restrict__ offg,
                                             int* __restrict__ csr,
                                             int* __restrict__ deg,
                                             float* __restrict__ dinv,
                                             int* __restrict__ offs) {
    __shared__ int cnt[NPB];
    __shared__ int loff[256];
    __shared__ int cur[NPB];
    const int b = blockIdx.x, t = threadIdx.x;
    const int s     = offg[b * NBLK];
    const int e_end = (b == NBUK - 1) ? NE : offg[(b + 1) * NBLK];
    const int nb0   = b * NPB;
    const int nnod  = min(NPB, NN - nb0);
    if (t < NPB) cnt[t] = 0;
    __syncthreads();
    for (int e = s + t; e < e_end; e += 256)
        atomicAdd(&cnt[pairs[e].y - nb0], 1);
    __syncthreads();
    int v = (t < NPB) ? cnt[t] : 0;
    loff[t] = v;
    __syncthreads();
    for (int off = 1; off < 256; off <<= 1) {
        int u = (t >= off) ? loff[t - off] : 0;
        __syncthreads();
        loff[t] += u;
        __syncthreads();
    }
    int myoff = loff[t] - v;
    __syncthreads();
    loff[t] = myoff;
    if (t < NPB) cur[t] = 0;
    __syncthreads();
    if (t < nnod) {
        int node = nb0 + t;
        int dg = cnt[t];
        deg[node]  = dg;
        dinv[node] = rsqrtf((float)(dg + 1));
        offs[node] = s + myoff;
    }
    for (int e = s + t; e < e_end; e += 256) {
        int2 pr = pairs[e];
        int li = pr.y - nb0;
        int p = atomicAdd(&cur[li], 1);
        csr[s + loff[li] + p] = pr.x;
    }
}

// ---------------- casts ----------------

__global__ void k_cast_scale_x(const float* __restrict__ x, const float* __restrict__ dinv,
                               unsigned short* __restrict__ xb, int n4) {
    int i = blockIdx.x * blockDim.x + threadIdx.x;
    if (i >= n4) return;
    float dv = dinv[i >> 5];
    const float4 v = *(const float4*)&x[i * 4];
    ushort4 o;
    o.x = f2bf(v.x * dv); o.y = f2bf(v.y * dv);
    o.z = f2bf(v.z * dv); o.w = f2bf(v.w * dv);
    *(ushort4*)&xb[i * 4] = o;
}

__global__ void k_cast_wt(const float* __restrict__ W, unsigned short* __restrict__ Wt, int K) {
    int i = blockIdx.x * blockDim.x + threadIdx.x;
    if (i >= K * HID) return;
    int k = i >> 8;
    int nc = i & 255;
    Wt[nc * K + k] = f2bf(W[i]);
}

// ---------------- MFMA GEMM with fused epilogue ----------------

template <int MODE>
__global__ __launch_bounds__(256) void k_gemm_mfma(const unsigned short* __restrict__ A,
                                                   const unsigned short* __restrict__ Wt,
                                                   const float* __restrict__ dinv,
                                                   const float* __restrict__ bias,
                                                   unsigned short* __restrict__ out,
                                                   int M, int K) {
    __shared__ unsigned short As[128 * 40];
    __shared__ unsigned short Bs[128 * 40];
    const int t = threadIdx.x;
    const int lane = t & 63;
    const int wid = t >> 6;
    const int wr = wid >> 1, wc = wid & 1;
    const int bm = blockIdx.x * 128, bn = blockIdx.y * 128;
    const int lr = lane & 15;
    const int ko = (lane >> 4) << 3;

    f32x4 acc[4][4] = {};

    const int r = t >> 2;
    const int kq = (t & 3) << 3;

    for (int kk = 0; kk < K; kk += 32) {
#pragma unroll
        for (int h = 0; h < 128; h += 64) {
            int row = bm + r + h;
            int4 v = make_int4(0, 0, 0, 0);
            if (row < M) v = *(const int4*)&A[(size_t)row * K + kk + kq];
            *(int4*)&As[(r + h) * 40 + kq] = v;
        }
#pragma unroll
        for (int h = 0; h < 128; h += 64) {
            int nrow = bn + r + h;
            int4 v = *(const int4*)&Wt[(size_t)nrow * K + kk + kq];
            *(int4*)&Bs[(r + h) * 40 + kq] = v;
        }
        __syncthreads();
        bf16x8 af[4], bfr[4];
#pragma unroll
        for (int mf = 0; mf < 4; ++mf)
            af[mf] = *(const bf16x8*)&As[(wr * 64 + mf * 16 + lr) * 40 + ko];
#pragma unroll
        for (int nf = 0; nf < 4; ++nf)
            bfr[nf] = *(const bf16x8*)&Bs[(wc * 64 + nf * 16 + lr) * 40 + ko];
#pragma unroll
        for (int mf = 0; mf < 4; ++mf)
#pragma unroll
            for (int nf = 0; nf < 4; ++nf)
                acc[mf][nf] = __builtin_amdgcn_mfma_f32_16x16x32_bf16(af[mf], bfr[nf], acc[mf][nf], 0, 0, 0);
        __syncthreads();
    }

#pragma unroll
    for (int mf = 0; mf < 4; ++mf) {
#pragma unroll
        for (int b = 0; b < 4; ++b) {
            int row = bm + wr * 64 + mf * 16 + (lane >> 4) * 4 + b;
            if (row >= M) continue;
            float dv = (MODE == 1) ? dinv[row] : 1.0f;
#pragma unroll
            for (int nf = 0; nf < 4; ++nf) {
                int col = bn + wc * 64 + nf * 16 + lr;
                float v = fmaxf(acc[mf][nf][b] + bias[col], 0.f);
                if (MODE == 1) v *= dv;
                out[(size_t)row * HID + col] = f2bf(v);
            }
        }
    }
}

// ---------------- aggregation, 256 channels, 8-deep MLP ----------------

__global__ __launch_bounds__(256) void k_agg256(const unsigned short* __restrict__ hs,
                                                const int* __restrict__ csr,
                                                const int* __restrict__ offs,
                                                const int* __restrict__ deg,
                                                const float* __restrict__ dinv,
                                                unsigned short* __restrict__ out, int n) {
    int wid = threadIdx.x >> 6, lane = threadIdx.x & 63;
    int node = blockIdx.x * 4 + wid;
    if (node >= n) return;
    int c = lane << 2;
    const ushort4 self = *(const ushort4*)&hs[(size_t)node * HID + c];
    float a0 = bf2f(self.x), a1 = bf2f(self.y), a2 = bf2f(self.z), a3 = bf2f(self.w);
    int s0 = offs[node], cnt = deg[node];
    for (int base = 0; base < cnt; base += 64) {
        int nb = min(64, cnt - base);
        int idx = (lane < nb) ? csr[s0 + base + lane] : 0;
        int i = 0;
        for (; i + 8 <= nb; i += 8) {
            ushort4 v[8];
#pragma unroll
            for (int k = 0; k < 8; ++k) {
                int j = __shfl(idx, i + k);
                v[k] = *(const ushort4*)&hs[(size_t)j * HID + c];
            }
#pragma unroll
            for (int k = 0; k < 8; ++k) {
                a0 += bf2f(v[k].x); a1 += bf2f(v[k].y);
                a2 += bf2f(v[k].z); a3 += bf2f(v[k].w);
            }
        }
        for (; i + 4 <= nb; i += 4) {
            ushort4 v[4];
#pragma unroll
            for (int k = 0; k < 4; ++k) {
                int j = __shfl(idx, i + k);
                v[k] = *(const ushort4*)&hs[(size_t)j * HID + c];
            }
#pragma unroll
            for (int k = 0; k < 4; ++k) {
                a0 += bf2f(v[k].x); a1 += bf2f(v[k].y);
                a2 += bf2f(v[k].z); a3 += bf2f(v[k].w);
            }
        }
        for (; i < nb; ++i) {
            int j = __shfl(idx, i);
            const ushort4 v = *(const ushort4*)&hs[(size_t)j * HID + c];
            a0 += bf2f(v.x); a1 += bf2f(v.y); a2 += bf2f(v.z); a3 += bf2f(v.w);
        }
    }
    float dv = dinv[node];
    ushort4 r;
    r.x = f2bf(dv * a0); r.y = f2bf(dv * a1);
    r.z = f2bf(dv * a2); r.w = f2bf(dv * a3);
    *(ushort4*)&out[(size_t)node * HID + c] = r;
}

// ---------------- aggregation, 128 channels, 8-deep (4 per 32-lane half) ----------------

__global__ __launch_bounds__(256) void k_agg128(const unsigned short* __restrict__ xs,
                                                const int* __restrict__ csr,
                                                const int* __restrict__ offs,
                                                const int* __restrict__ deg,
                                                const float* __restrict__ dinv,
                                                unsigned short* __restrict__ out, int n) {
    int wid = threadIdx.x >> 6, lane = threadIdx.x & 63;
    int node = blockIdx.x * 4 + wid;
    if (node >= n) return;
    int half = lane >> 5, l32 = lane & 31;
    int c = l32 << 2;
    float a0 = 0.f, a1 = 0.f, a2 = 0.f, a3 = 0.f;
    if (half == 0) {
        const ushort4 s = *(const ushort4*)&xs[(size_t)node * DIN + c];
        a0 = bf2f(s.x); a1 = bf2f(s.y); a2 = bf2f(s.z); a3 = bf2f(s.w);
    }
    int s0 = offs[node], cnt = deg[node];
    for (int base = 0; base < cnt; base += 64) {
        int nb = min(64, cnt - base);
        int idx = (lane < nb) ? csr[s0 + base + lane] : 0;
        int i = 0;
        for (; i + 8 <= nb; i += 8) {
            ushort4 v[4];
#pragma unroll
            for (int k = 0; k < 4; ++k) {
                int j = __shfl(idx, i + 2 * k + half);
                v[k] = *(const ushort4*)&xs[(size_t)j * DIN + c];
            }
#pragma unroll
            for (int k = 0; k < 4; ++k) {
                a0 += bf2f(v[k].x); a1 += bf2f(v[k].y);
                a2 += bf2f(v[k].z); a3 += bf2f(v[k].w);
            }
        }
        for (; i < nb; i += 2) {
            int e = i + half;
            int j = __shfl(idx, e < nb ? e : 0);
            if (e < nb) {
                const ushort4 v = *(const ushort4*)&xs[(size_t)j * DIN + c];
                a0 += bf2f(v.x); a1 += bf2f(v.y); a2 += bf2f(v.z); a3 += bf2f(v.w);
            }
        }
    }
    a0 += __shfl_xor(a0, 32);
    a1 += __shfl_xor(a1, 32);
    a2 += __shfl_xor(a2, 32);
    a3 += __shfl_xor(a3, 32);
    if (half == 0) {
        float dv = dinv[node];
        ushort4 r;
        r.x = f2bf(dv * a0); r.y = f2bf(dv * a1);
        r.z = f2bf(dv * a2); r.w = f2bf(dv * a3);
        *(ushort4*)&out[(size_t)node * DIN + c] = r;
    }
}

// ---------------- pooling ----------------

__global__ __launch_bounds__(256) void k_pool(const unsigned short* __restrict__ a,
                                              const int* __restrict__ batch,
                                              float* __restrict__ pooled,
                                              float* __restrict__ countsf, int n) {
    int wid = threadIdx.x >> 6, lane = threadIdx.x & 63;
    int wg = blockIdx.x * 4 + wid;
    int n0 = wg * 16;
    if (n0 >= n) return;
    int n1 = min(n0 + 16, n);
    int c = lane << 2;
    float ax = 0.f, ay = 0.f, az = 0.f, aw = 0.f;
    int gcur = -1; float run = 0.f;
    for (int nd = n0; nd < n1; ++nd) {
        int g = batch[nd];
        if (g != gcur) {
            if (gcur >= 0) {
                atomicAdd(&pooled[gcur * HID + c + 0], ax);
                atomicAdd(&pooled[gcur * HID + c + 1], ay);
                atomicAdd(&pooled[gcur * HID + c + 2], az);
                atomicAdd(&pooled[gcur * HID + c + 3], aw);
                if (lane == 0) atomicAdd(&countsf[gcur], run);
            }
            gcur = g; ax = ay = az = aw = 0.f; run = 0.f;
        }
        const ushort4 v = *(const ushort4*)&a[(size_t)nd * HID + c];
        ax += bf2f(v.x); ay += bf2f(v.y); az += bf2f(v.z); aw += bf2f(v.w);
        run += 1.f;
    }
    if (gcur >= 0) {
        atomicAdd(&pooled[gcur * HID + c + 0], ax);
        atomicAdd(&pooled[gcur * HID + c + 1], ay);
        atomicAdd(&pooled[gcur * HID + c + 2], az);
        atomicAdd(&pooled[gcur * HID + c + 3], aw);
        if (lane == 0) atomicAdd(&countsf[gcur], run);
    }
}

// ---------------- head MLP ----------------

__global__ __launch_bounds__(256) void k_mlp(const float* __restrict__ pooled,
                                             const float* __restrict__ countsf,
                                             const float* __restrict__ Wf1,
                                             const float* __restrict__ bf1,
                                             const float* __restrict__ Wf2,
                                             const float* __restrict__ bf2,
                                             float* __restrict__ out) {
    __shared__ float p[HID];
    __shared__ float z[HID];
    int g = blockIdx.x, t = threadIdx.x;
    float cnt = fmaxf(countsf[g], 1.0f);
    p[t] = pooled[g * HID + t] / cnt;
    __syncthreads();
    float accz = bf1[t];
    for (int k = 0; k < HID; ++k)
        accz = fmaf(p[k], Wf1[k * HID + t], accz);
    z[t] = fmaxf(accz, 0.f);
    __syncthreads();
    if (t < NCLS) {
        float o = bf2[t];
        for (int k = 0; k < HID; ++k)
            o = fmaf(z[k], Wf2[k * NCLS + t], o);
        float sp = fmaxf(o, 0.f) + log1pf(expf(-fabsf(o)));
        out[g * NCLS + t] = sp + 0.001f;
    }
}

// ---------------- launch ----------------

extern "C" void kernel_launch(void* const* d_in, const int* in_sizes, int n_in,
                              void* d_out, int out_size, void* d_ws, size_t ws_size,
                              hipStream_t stream) {
    const float* x     = (const float*)d_in[0];
    const int*   ei    = (const int*)d_in[1];
    const int*   batch = (const int*)d_in[2];
    const float* W1    = (const float*)d_in[3];
    const float* b1    = (const float*)d_in[4];
    const float* W2    = (const float*)d_in[5];
    const float* b2    = (const float*)d_in[6];
    const float* Wf1   = (const float*)d_in[7];
    const float* bf1   = (const float*)d_in[8];
    const float* Wf2   = (const float*)d_in[9];
    const float* bf2   = (const float*)d_in[10];
    float* out = (float*)d_out;

    const int* srcv = ei;
    const int* dstv = ei + NE;

    char* p = (char*)d_ws;
    auto take = [&](size_t bytes) -> char* {
        char* q = p; p += (bytes + 255) & ~(size_t)255; return q;
    };
    unsigned short* big0 = (unsigned short*)take((size_t)NN * HID * 2);
    unsigned short* big1 = (unsigned short*)take((size_t)NN * HID * 2);
    unsigned short* xs = big0;
    unsigned short* xa = big0 + (size_t)NN * DIN;
    unsigned short* hB = big1;
    unsigned short* rB = big0;
    unsigned short* o2 = big1;
    int2* pairs = (int2*)big1;
    unsigned short* wt1  = (unsigned short*)take((size_t)DIN * HID * 2);
    unsigned short* wt2  = (unsigned short*)take((size_t)HID * HID * 2);
    int*   histg   = (int*)take((size_t)NBUK * NBLK * 4);
    int*   deg     = (int*)take((size_t)NN * 4);
    int*   offs    = (int*)take((size_t)NN * 4);
    int*   csr     = (int*)take((size_t)NE * 4);
    float* dinv    = (float*)take((size_t)NN * 4);
    float* pooled  = (float*)take((size_t)NG * HID * 4);
    float* countsf = (float*)take((size_t)NG * 4);

    hipMemsetAsync(pooled, 0, (size_t)NG * HID * 4, stream);
    hipMemsetAsync(countsf, 0, (size_t)NG * 4, stream);

    k_hist<<<NBLK, 256, 0, stream>>>(dstv, histg);
    k_scan64k<<<1, 1024, 0, stream>>>(histg);
    k_scatter<<<NBLK, 256, 0, stream>>>(srcv, dstv, histg, pairs);
    k_csr<<<NBUK, 256, 0, stream>>>(pairs, histg, csr, deg, dinv, offs);

    k_cast_scale_x<<<(NN * DIN / 4 + 255) / 256, 256, 0, stream>>>(x, dinv, xs, NN * DIN / 4);
    k_cast_wt<<<(DIN * HID + 255) / 256, 256, 0, stream>>>(W1, wt1, DIN);
    k_cast_wt<<<(HID * HID + 255) / 256, 256, 0, stream>>>(W2, wt2, HID);

    dim3 gg((NN + 127) / 128, HID / 128);
    k_agg128<<<(NN + 3) / 4, 256, 0, stream>>>(xs, csr, offs, deg, dinv, xa, NN);
    k_gemm_mfma<1><<<gg, 256, 0, stream>>>(xa, wt1, dinv, b1, hB, NN, DIN);
    k_agg256<<<(NN + 3) / 4, 256, 0, stream>>>(hB, csr, offs, deg, dinv, rB, NN);
    k_gemm_mfma<2><<<gg, 256, 0, stream>>>(rB, wt2, dinv, b2, o2, NN, HID);

    int pool_waves  = (NN + 15) / 16;
    int pool_blocks = (pool_waves + 3) / 4;
    k_pool<<<pool_blocks, 256, 0, stream>>>(o2, batch, pooled, countsf, NN);
    k_mlp<<<NG, 256, 0, stream>>>(pooled, countsf, Wf1, bf1, Wf2, bf2, out);
}